// Round 4
// baseline (483.073 us; speedup 1.0000x reference)
//
#include <hip/hip_runtime.h>
#include <hip/hip_bf16.h>

#define BB 8
#define EMBED 384
#define NH 32
#define HD 12
#define HWN 1024
#define HIDDEN 512
#define CAT 768
#define SCALE 0.28867513459481287f

typedef __attribute__((ext_vector_type(8))) unsigned short ushort8;
typedef __attribute__((ext_vector_type(8))) short short8;
typedef __attribute__((ext_vector_type(4))) float f32x4;
typedef __attribute__((ext_vector_type(4))) unsigned short ushort4v;

static __device__ __forceinline__ float bf2f(unsigned short u) {
    return __uint_as_float(((unsigned int)u) << 16);
}
static __device__ __forceinline__ unsigned short f2bf(float f) {
    unsigned int u = __float_as_uint(f);
    u = u + 0x7FFFu + ((u >> 16) & 1u);   // RNE
    return (unsigned short)(u >> 16);
}

// ---------------- f32 -> bf16 convert: all 7 weight matrices in one launch ----------------
struct WConv {
    const float* src[7];
    unsigned short* dst[7];
    int n4[7];      // element count / 4
    int start[8];   // prefix over n4, start[7] = total
};

__global__ __launch_bounds__(256) void k_bf16_all(WConv wc) {
    int i = blockIdx.x * 256 + threadIdx.x;
    if (i >= wc.start[7]) return;
    int p = 0;
#pragma unroll
    for (int j = 1; j < 7; ++j) p += (i >= wc.start[j]);
    const int e = i - wc.start[p];
    const f32x4 v = reinterpret_cast<const f32x4*>(wc.src[p])[e];
    ushort4v o;
#pragma unroll
    for (int j = 0; j < 4; ++j) o[j] = f2bf(v[j]);
    reinterpret_cast<ushort4v*>(wc.dst[p])[e] = o;
}

// ---------------- transpose x (B,C,HW) f32 -> Xt (B,HW,C) bf16 ----------------
__global__ __launch_bounds__(256) void k_transpose(const float* __restrict__ x0, const float* __restrict__ x1,
                                                   unsigned short* __restrict__ t0, unsigned short* __restrict__ t1) {
    __shared__ float tile[32][33];
    const int z = blockIdx.z;
    const int s = z >> 3, b = z & 7;
    const float* src = (s ? x1 : x0) + (size_t)b * EMBED * HWN;
    unsigned short* dst = (s ? t1 : t0) + (size_t)b * HWN * EMBED;
    const int c0 = blockIdx.x * 32;
    const int n0 = blockIdx.y * 32;
    const int tc = threadIdx.x & 31;
    const int tr = threadIdx.x >> 5;
#pragma unroll
    for (int p = 0; p < 4; ++p) {
        int r = tr + p * 8;
        tile[r][tc] = src[(size_t)(c0 + r) * HWN + n0 + tc];
    }
    __syncthreads();
#pragma unroll
    for (int p = 0; p < 4; ++p) {
        int r = tr + p * 8;
        dst[(size_t)(n0 + r) * EMBED + c0 + tc] = f2bf(tile[tc][r]);
    }
}

// ---------------- bf16 MFMA GEMM core: out[o][n] = sum_k A[o][k]*Bt[n][k] + bias[o] ----------------
// BM=BN=BK=64, 256 threads (4 waves, 2x2), each wave 32x32 via 2x2 16x16x32 MFMA frags.
template <bool F32OUT>
static __device__ __forceinline__ void gemm_core(const unsigned short* __restrict__ A,
                                                 const unsigned short* __restrict__ Bt,
                                                 const float* __restrict__ bias,
                                                 unsigned short* __restrict__ outBf,
                                                 float* __restrict__ outF,
                                                 int K, int bx, int by) {
    __shared__ unsigned short As[64][72];   // +8 pad: 144B row stride -> conflict-free-ish b128 reads
    __shared__ unsigned short Bs[64][72];
    const int t = threadIdx.x;
    const int lane = t & 63;
    const int wid = t >> 6;
    const int wr = wid >> 1, wc = wid & 1;
    const int o0 = bx * 64, n0 = by * 64;
    const int lrow = t >> 2;   // 0..63
    const int lseg = t & 3;    // 16 elems each

    f32x4 acc[2][2] = {};

    for (int k0 = 0; k0 < K; k0 += 64) {
        const ushort8* ga = reinterpret_cast<const ushort8*>(A + (size_t)(o0 + lrow) * K + k0 + lseg * 16);
        const ushort8* gb = reinterpret_cast<const ushort8*>(Bt + (size_t)(n0 + lrow) * K + k0 + lseg * 16);
        ushort8 a0 = ga[0], a1 = ga[1];
        ushort8 b0 = gb[0], b1 = gb[1];
        *reinterpret_cast<ushort8*>(&As[lrow][lseg * 16]) = a0;
        *reinterpret_cast<ushort8*>(&As[lrow][lseg * 16 + 8]) = a1;
        *reinterpret_cast<ushort8*>(&Bs[lrow][lseg * 16]) = b0;
        *reinterpret_cast<ushort8*>(&Bs[lrow][lseg * 16 + 8]) = b1;
        __syncthreads();
#pragma unroll
        for (int kk = 0; kk < 2; ++kk) {
            const int ko = kk * 32 + ((lane >> 4) << 3);
            short8 af[2], bfv[2];
            af[0]  = *reinterpret_cast<const short8*>(&As[wr * 32 + (lane & 15)][ko]);
            af[1]  = *reinterpret_cast<const short8*>(&As[wr * 32 + 16 + (lane & 15)][ko]);
            bfv[0] = *reinterpret_cast<const short8*>(&Bs[wc * 32 + (lane & 15)][ko]);
            bfv[1] = *reinterpret_cast<const short8*>(&Bs[wc * 32 + 16 + (lane & 15)][ko]);
#pragma unroll
            for (int i = 0; i < 2; ++i)
#pragma unroll
                for (int j = 0; j < 2; ++j)
                    acc[i][j] = __builtin_amdgcn_mfma_f32_16x16x32_bf16(af[i], bfv[j], acc[i][j], 0, 0, 0);
        }
        __syncthreads();
    }
#pragma unroll
    for (int i = 0; i < 2; ++i) {
#pragma unroll
        for (int j = 0; j < 2; ++j) {
            const int ob = o0 + wr * 32 + i * 16 + ((lane >> 4) << 2);
            const int n  = n0 + wc * 32 + j * 16 + (lane & 15);
#pragma unroll
            for (int r = 0; r < 4; ++r) {
                const int o = ob + r;
                float v = acc[i][j][r] + bias[o];
                if constexpr (F32OUT) outF[(size_t)o * HWN + n] = v;
                else                  outBf[(size_t)o * HWN + n] = f2bf(v);
            }
        }
    }
}

struct QkvTable {
    const unsigned short* W[6];
    const float* bias[6];
    const unsigned short* Xt[2];
    unsigned short* out[6];
};

__global__ __launch_bounds__(256) void k_gemm_qkv(QkvTable tab) {
    const int z = blockIdx.z;
    const int b = z / 6, p = z % 6;
    gemm_core<false>(tab.W[p],
                     tab.Xt[p / 3] + (size_t)b * HWN * EMBED,
                     tab.bias[p],
                     tab.out[p] + (size_t)b * EMBED * HWN,
                     nullptr,
                     EMBED, blockIdx.x, blockIdx.y);
}

__global__ __launch_bounds__(256) void k_gemm_out(const unsigned short* __restrict__ Wo,
                                                  const unsigned short* __restrict__ fused,
                                                  const float* __restrict__ bo,
                                                  float* __restrict__ out) {
    const int b = blockIdx.z;
    gemm_core<true>(Wo,
                    fused + (size_t)b * HWN * CAT,
                    bo,
                    nullptr,
                    out + (size_t)b * HIDDEN * HWN,
                    CAT, blockIdx.x, blockIdx.y);
}

// ---------------- scalar online-softmax flash attention ----------------
// grid 512 = branch(2) x b(8) x h(32); 512 threads; each thread owns 2 query rows.
// K/V staged in LDS f32 (m,d) layout, chunked 2x512 -> 48KB.
__global__ __launch_bounds__(512) void k_attn(const unsigned short* __restrict__ qc,
                                              const unsigned short* __restrict__ kc,
                                              const unsigned short* __restrict__ vc,
                                              const unsigned short* __restrict__ qcb,
                                              const unsigned short* __restrict__ kcb,
                                              const unsigned short* __restrict__ vcb,
                                              const float* __restrict__ x,
                                              const float* __restrict__ xb,
                                              unsigned short* __restrict__ fused) {
    __shared__ float kv[512][24];   // [m][0..11]=K, [m][12..23]=V
    const int z = blockIdx.x;
    const int branch = z >> 8;
    const int b = (z >> 5) & 7;
    const int h = z & 31;
    const unsigned short* Q  = branch ? qc  : qcb;
    const unsigned short* Ks = branch ? kcb : kc;
    const unsigned short* Vs = branch ? vcb : vc;
    const float* res = branch ? xb : x;
    const int coff = branch ? EMBED : 0;
    const size_t base = ((size_t)b * EMBED + h * HD) * HWN;
    const int t = threadIdx.x;
    const float NEG_INF = -__builtin_inff();

    float ql[2][HD], o[2][HD], mx[2], sm[2];
#pragma unroll
    for (int r = 0; r < 2; ++r) {
        const int n = t + r * 512;
#pragma unroll
        for (int d = 0; d < HD; ++d) {
            ql[r][d] = bf2f(Q[base + (size_t)d * HWN + n]) * SCALE;
            o[r][d] = 0.f;
        }
        mx[r] = NEG_INF;
        sm[r] = 0.f;
    }

    for (int mc = 0; mc < 2; ++mc) {
        const int m0 = mc * 512;
        __syncthreads();
#pragma unroll
        for (int j = 0; j < HD; ++j) {
            kv[t][j]      = bf2f(Ks[base + (size_t)j * HWN + m0 + t]);
            kv[t][HD + j] = bf2f(Vs[base + (size_t)j * HWN + m0 + t]);
        }
        __syncthreads();
        for (int m = 0; m < 512; ++m) {
            float kd[HD], vd[HD];
            const float* km = &kv[m][0];
#pragma unroll
            for (int d = 0; d < HD; ++d) { kd[d] = km[d]; vd[d] = km[HD + d]; }
#pragma unroll
            for (int r = 0; r < 2; ++r) {
                float s = 0.f;
#pragma unroll
                for (int d = 0; d < HD; ++d) s = fmaf(ql[r][d], kd[d], s);
                if (s > mx[r]) {
                    const float f = __expf(mx[r] - s);   // expf(-inf)=0 handles init
                    sm[r] = fmaf(sm[r], f, 1.0f);
#pragma unroll
                    for (int d = 0; d < HD; ++d) o[r][d] = fmaf(o[r][d], f, vd[d]);
                    mx[r] = s;
                } else {
                    const float p = __expf(s - mx[r]);
                    sm[r] += p;
#pragma unroll
                    for (int d = 0; d < HD; ++d) o[r][d] = fmaf(p, vd[d], o[r][d]);
                }
            }
        }
    }

#pragma unroll
    for (int r = 0; r < 2; ++r) {
        const int n = t + r * 512;
        const float inv = 1.0f / sm[r];
        const size_t ob = ((size_t)b * HWN + n) * CAT + coff + h * HD;
#pragma unroll
        for (int d = 0; d < HD; ++d)
            fused[ob + d] = f2bf(fmaf(o[r][d], inv, res[base + (size_t)d * HWN + n]));
    }
}

extern "C" void kernel_launch(void* const* d_in, const int* in_sizes, int n_in,
                              void* d_out, int out_size, void* d_ws, size_t ws_size,
                              hipStream_t stream) {
    (void)in_sizes; (void)n_in; (void)out_size; (void)ws_size;
    const float* x   = (const float*)d_in[0];
    const float* xbp = (const float*)d_in[1];
    const float* Wq  = (const float*)d_in[2];  const float* bq  = (const float*)d_in[3];
    const float* Wk  = (const float*)d_in[4];  const float* bk  = (const float*)d_in[5];
    const float* Wv  = (const float*)d_in[6];  const float* bv  = (const float*)d_in[7];
    const float* Wqb = (const float*)d_in[8];  const float* bqb = (const float*)d_in[9];
    const float* Wkb = (const float*)d_in[10]; const float* bkb = (const float*)d_in[11];
    const float* Wvb = (const float*)d_in[12]; const float* bvb = (const float*)d_in[13];
    const float* Wo  = (const float*)d_in[14]; const float* bo  = (const float*)d_in[15];
    float* out = (float*)d_out;

    char* ws = (char*)d_ws;
    size_t off = 0;
    auto alloc = [&](size_t bytes) -> void* {
        void* p = ws + off;
        off = (off + bytes + 255) & ~(size_t)255;
        return p;
    };
    unsigned short* wbf[6];
    for (int i = 0; i < 6; ++i) wbf[i] = (unsigned short*)alloc((size_t)EMBED * EMBED * 2);
    unsigned short* wobf = (unsigned short*)alloc((size_t)HIDDEN * CAT * 2);
    unsigned short* xt0  = (unsigned short*)alloc((size_t)BB * HWN * EMBED * 2);
    unsigned short* xt1  = (unsigned short*)alloc((size_t)BB * HWN * EMBED * 2);
    unsigned short* qkv[6];
    for (int i = 0; i < 6; ++i) qkv[i] = (unsigned short*)alloc((size_t)BB * EMBED * HWN * 2);
    unsigned short* fused = (unsigned short*)alloc((size_t)BB * HWN * CAT * 2);

    // 1) weights -> bf16 (single launch, float4-vectorized)
    WConv wc;
    const float* wsrc[7] = {Wq, Wk, Wv, Wqb, Wkb, Wvb, Wo};
    unsigned short* wdst[7] = {wbf[0], wbf[1], wbf[2], wbf[3], wbf[4], wbf[5], wobf};
    int acc4 = 0;
    for (int i = 0; i < 7; ++i) {
        const int n = (i < 6) ? EMBED * EMBED : HIDDEN * CAT;
        wc.src[i] = wsrc[i];
        wc.dst[i] = wdst[i];
        wc.n4[i] = n / 4;
        wc.start[i] = acc4;
        acc4 += n / 4;
    }
    wc.start[7] = acc4;
    k_bf16_all<<<(acc4 + 255) / 256, 256, 0, stream>>>(wc);

    // 2) x, x_bpf -> token-major bf16
    k_transpose<<<dim3(EMBED / 32, HWN / 32, 16), 256, 0, stream>>>(x, xbp, xt0, xt1);

    // 3) six QKV projections
    QkvTable tab;
    tab.W[0] = wbf[0]; tab.W[1] = wbf[1]; tab.W[2] = wbf[2];
    tab.W[3] = wbf[3]; tab.W[4] = wbf[4]; tab.W[5] = wbf[5];
    tab.bias[0] = bq; tab.bias[1] = bk; tab.bias[2] = bv;
    tab.bias[3] = bqb; tab.bias[4] = bkb; tab.bias[5] = bvb;
    tab.Xt[0] = xt0; tab.Xt[1] = xt1;
    for (int i = 0; i < 6; ++i) tab.out[i] = qkv[i];
    k_gemm_qkv<<<dim3(EMBED / 64, HWN / 64, BB * 6), 256, 0, stream>>>(tab);

    // 4) both cross-attention branches + residual -> fused (token-major bf16)
    k_attn<<<dim3(512), 512, 0, stream>>>(qkv[0], qkv[1], qkv[2], qkv[3], qkv[4], qkv[5],
                                          x, xbp, fused);

    // 5) output projection -> f32 d_out
    k_gemm_out<<<dim3(HIDDEN / 64, HWN / 64, BB), 256, 0, stream>>>(wobf, fused, bo, out);
}

// Round 5
// 287.346 us; speedup vs baseline: 1.6812x; 1.6812x over previous
//
#include <hip/hip_runtime.h>
#include <hip/hip_bf16.h>

#define BB 8
#define EMBED 384
#define NH 32
#define HD 12
#define HWN 1024
#define HIDDEN 512
#define KTOT 1536
#define SCALE 0.28867513459481287f

typedef __attribute__((ext_vector_type(8))) unsigned short ushort8;
typedef __attribute__((ext_vector_type(8))) short short8;
typedef __attribute__((ext_vector_type(4))) float f32x4;
typedef __attribute__((ext_vector_type(4))) unsigned short ushort4v;
typedef __attribute__((ext_vector_type(2))) unsigned int uint2v;

static __device__ __forceinline__ float bf2f(unsigned short u) {
    return __uint_as_float(((unsigned int)u) << 16);
}
static __device__ __forceinline__ unsigned short f2bf(float f) {
    unsigned int u = __float_as_uint(f);
    u = u + 0x7FFFu + ((u >> 16) & 1u);   // RNE
    return (unsigned short)(u >> 16);
}

// ---------------- f32 -> bf16 weights; Wo duplicated into Wo2[512][1536] ----------------
struct WConv {
    const float* src[7];
    unsigned short* dst[7];
    int start[8];   // prefix over vec4 counts
};

__global__ __launch_bounds__(256) void k_bf16_all(WConv wc) {
    int i = blockIdx.x * 256 + threadIdx.x;
    if (i >= wc.start[7]) return;
    int p = 0;
#pragma unroll
    for (int j = 1; j < 7; ++j) p += (i >= wc.start[j]);
    const int e = i - wc.start[p];
    const f32x4 v = reinterpret_cast<const f32x4*>(wc.src[p])[e];
    ushort4v o;
#pragma unroll
    for (int j = 0; j < 4; ++j) o[j] = f2bf(v[j]);
    if (p == 6) {
        // Wo (512x768): write to Wo2[o][c] and Wo2[o][768+c]  (row = 384 vec4)
        const int row = e / 192, cc = e % 192;
        ushort4v* d = reinterpret_cast<ushort4v*>(wc.dst[6]);
        d[row * 384 + cc] = o;
        d[row * 384 + 192 + cc] = o;
    } else {
        reinterpret_cast<ushort4v*>(wc.dst[p])[e] = o;
    }
}

// ---------------- transpose x (B,C,HW) f32 -> fused2[b][n][768 + s*384 + c] bf16 ----------------
__global__ __launch_bounds__(256) void k_transpose(const float* __restrict__ x0, const float* __restrict__ x1,
                                                   unsigned short* __restrict__ fused2) {
    __shared__ float tile[32][33];
    const int z = blockIdx.z;
    const int s = z >> 3, b = z & 7;
    const float* src = (s ? x1 : x0) + (size_t)b * EMBED * HWN;
    unsigned short* dst = fused2 + (size_t)b * HWN * KTOT + 768 + s * 384;
    const int c0 = blockIdx.x * 32;
    const int n0 = blockIdx.y * 32;
    const int tc = threadIdx.x & 31;
    const int tr = threadIdx.x >> 5;
#pragma unroll
    for (int p = 0; p < 4; ++p) {
        int r = tr + p * 8;
        tile[r][tc] = src[(size_t)(c0 + r) * HWN + n0 + tc];
    }
    __syncthreads();
#pragma unroll
    for (int p = 0; p < 4; ++p) {
        int r = tr + p * 8;
        dst[(size_t)(n0 + r) * KTOT + c0 + tc] = f2bf(tile[tc][r]);
    }
}

// ---------------- bf16 MFMA GEMM: out[o][n] = sum_k A[o][k]*Bt[n][k] + bias[o] ----------------
template <bool F32OUT>
static __device__ __forceinline__ void gemm_core(const unsigned short* __restrict__ A, int lda,
                                                 const unsigned short* __restrict__ Bt, int ldb,
                                                 const float* __restrict__ bias,
                                                 unsigned short* __restrict__ outBf,
                                                 float* __restrict__ outF,
                                                 int K, int bx, int by) {
    __shared__ unsigned short As[64][72];
    __shared__ unsigned short Bs[64][72];
    const int t = threadIdx.x;
    const int lane = t & 63;
    const int wid = t >> 6;
    const int wr = wid >> 1, wc = wid & 1;
    const int o0 = bx * 64, n0 = by * 64;
    const int lrow = t >> 2;
    const int lseg = t & 3;

    f32x4 acc[2][2] = {};

    for (int k0 = 0; k0 < K; k0 += 64) {
        const ushort8* ga = reinterpret_cast<const ushort8*>(A + (size_t)(o0 + lrow) * lda + k0 + lseg * 16);
        const ushort8* gb = reinterpret_cast<const ushort8*>(Bt + (size_t)(n0 + lrow) * ldb + k0 + lseg * 16);
        ushort8 a0 = ga[0], a1 = ga[1];
        ushort8 b0 = gb[0], b1 = gb[1];
        *reinterpret_cast<ushort8*>(&As[lrow][lseg * 16]) = a0;
        *reinterpret_cast<ushort8*>(&As[lrow][lseg * 16 + 8]) = a1;
        *reinterpret_cast<ushort8*>(&Bs[lrow][lseg * 16]) = b0;
        *reinterpret_cast<ushort8*>(&Bs[lrow][lseg * 16 + 8]) = b1;
        __syncthreads();
#pragma unroll
        for (int kk = 0; kk < 2; ++kk) {
            const int ko = kk * 32 + ((lane >> 4) << 3);
            short8 af[2], bfv[2];
            af[0]  = *reinterpret_cast<const short8*>(&As[wr * 32 + (lane & 15)][ko]);
            af[1]  = *reinterpret_cast<const short8*>(&As[wr * 32 + 16 + (lane & 15)][ko]);
            bfv[0] = *reinterpret_cast<const short8*>(&Bs[wc * 32 + (lane & 15)][ko]);
            bfv[1] = *reinterpret_cast<const short8*>(&Bs[wc * 32 + 16 + (lane & 15)][ko]);
#pragma unroll
            for (int i = 0; i < 2; ++i)
#pragma unroll
                for (int j = 0; j < 2; ++j)
                    acc[i][j] = __builtin_amdgcn_mfma_f32_16x16x32_bf16(af[i], bfv[j], acc[i][j], 0, 0, 0);
        }
        __syncthreads();
    }
#pragma unroll
    for (int i = 0; i < 2; ++i) {
#pragma unroll
        for (int j = 0; j < 2; ++j) {
            const int ob = o0 + wr * 32 + i * 16 + ((lane >> 4) << 2);
            const int n  = n0 + wc * 32 + j * 16 + (lane & 15);
#pragma unroll
            for (int r = 0; r < 4; ++r) {
                const int o = ob + r;
                float v = acc[i][j][r] + bias[o];
                if constexpr (F32OUT) outF[(size_t)o * HWN + n] = v;
                else                  outBf[(size_t)o * HWN + n] = f2bf(v);
            }
        }
    }
}

struct QkvTable {
    const unsigned short* W[6];
    const float* bias[6];
    const unsigned short* fused2;
    unsigned short* out[6];
};

__global__ __launch_bounds__(256) void k_gemm_qkv(QkvTable tab) {
    const int z = blockIdx.z;
    const int b = z / 6, p = z % 6;
    const unsigned short* Bt = tab.fused2 + (size_t)b * HWN * KTOT + 768 + (p / 3) * 384;
    gemm_core<false>(tab.W[p], EMBED, Bt, KTOT, tab.bias[p],
                     tab.out[p] + (size_t)b * EMBED * HWN, nullptr,
                     EMBED, blockIdx.x, blockIdx.y);
}

__global__ __launch_bounds__(256) void k_gemm_out(const unsigned short* __restrict__ Wo2,
                                                  const unsigned short* __restrict__ fused2,
                                                  const float* __restrict__ bo,
                                                  float* __restrict__ out) {
    const int b = blockIdx.z;
    gemm_core<true>(Wo2, KTOT, fused2 + (size_t)b * HWN * KTOT, KTOT, bo,
                    nullptr, out + (size_t)b * HIDDEN * HWN,
                    KTOT, blockIdx.x, blockIdx.y);
}

// ---------------- MFMA flash attention (no-max softmax, d=12 zero-padded) ----------------
// grid 2048 = instance(512: branch x b x h) x qtile(4, 256 q-rows); 256 threads = 4 waves.
// Wave w owns q-rows [w*64, w*64+64): 4 subtiles of 16. K/V staged per 512-m phase.
__global__ __launch_bounds__(256) void k_attn_mfma(const unsigned short* __restrict__ qc,
                                                   const unsigned short* __restrict__ kc,
                                                   const unsigned short* __restrict__ vc,
                                                   const unsigned short* __restrict__ qcb,
                                                   const unsigned short* __restrict__ kcb,
                                                   const unsigned short* __restrict__ vcb,
                                                   unsigned short* __restrict__ fused2) {
    __shared__ unsigned short Qs[16][256];     // [d][n], rows 12-15 zero
    __shared__ unsigned short Ks[512][16];     // [m][d], cols 12-15 zero
    __shared__ unsigned short Vs[12][520];     // [d][m], row-padded for banks
    __shared__ unsigned short Ps[4][2560];     // per-wave P [64][40] bf16; reused as Ot [12][68]

    const int bid = blockIdx.x;
    const int inst = bid >> 2, qt = bid & 3;
    const int branch = inst >> 8, b = (inst >> 5) & 7, h = inst & 31;
    const unsigned short* Qg = branch ? qc : qcb;
    const unsigned short* Kg = branch ? kcb : kc;
    const unsigned short* Vg = branch ? vcb : vc;
    const int coff = branch ? 384 : 0;
    const size_t base = ((size_t)b * EMBED + h * HD) * HWN;
    const int t = threadIdx.x;
    const int lane = t & 63, w = t >> 6;
    const int c15 = lane & 15, g = lane >> 4;
    const int n0 = qt * 256;
    const bool ldA = lane < 32;             // frag lanes with real (k<16) data
    const float C2 = SCALE * 1.4426950408889634f;   // fold scale into exp2

    // stage Q [d][256]
#pragma unroll
    for (int d = 0; d < 12; ++d) Qs[d][t] = Qg[base + (size_t)d * HWN + n0 + t];
#pragma unroll
    for (int d = 12; d < 16; ++d) Qs[d][t] = 0;

    short8 af[4];
    f32x4 acc_o[4] = {};
    f32x4 ps[4] = {};
    unsigned short* Pw = &Ps[w][0];
    const int vrow = (c15 < 12) ? c15 : 11;   // clamp: cols 12-15 of PV are discarded

    for (int phase = 0; phase < 2; ++phase) {
        const int m0 = phase << 9;
        __syncthreads();   // prior-phase reads done (and Qs writes on phase 0)
        // stage K transposed [m][16]
#pragma unroll
        for (int i = 0; i < 24; ++i) {
            const int idx = i * 256 + t;
            const int mm = idx & 511, d = idx >> 9;
            Ks[mm][d] = Kg[base + (size_t)d * HWN + m0 + mm];
        }
#pragma unroll
        for (int i = 0; i < 8; ++i) {
            const int idx = i * 256 + t;
            Ks[idx >> 2][12 + (idx & 3)] = 0;
        }
        // stage V [d][512] (straight copy, vectorized)
#pragma unroll
        for (int i = 0; i < 3; ++i) {
            const int idx = i * 256 + t;
            const int d = idx >> 6, m8 = (idx & 63) << 3;
            *reinterpret_cast<ushort8*>(&Vs[d][m8]) =
                *reinterpret_cast<const ushort8*>(&Vg[base + (size_t)d * HWN + m0 + m8]);
        }
        __syncthreads();

        if (phase == 0) {
            // Q A-frags: row = n (lane&15), k = d; lanes>=32 are the d>=16 zero region
#pragma unroll
            for (int i = 0; i < 4; ++i) {
                short8 v = {};
                if (ldA) {
#pragma unroll
                    for (int j = 0; j < 8; ++j)
                        v[j] = (short)Qs[g * 8 + j][w * 64 + i * 16 + c15];
                }
                af[i] = v;
            }
        }

        for (int mc = 0; mc < 16; ++mc) {
            const int mb = mc << 5;
            short8 bk0 = {}, bk1 = {};
            if (ldA) {
                bk0 = *reinterpret_cast<const short8*>(&Ks[mb + c15][g * 8]);
                bk1 = *reinterpret_cast<const short8*>(&Ks[mb + 16 + c15][g * 8]);
            }
            const f32x4 z4 = {0.f, 0.f, 0.f, 0.f};
#pragma unroll
            for (int i = 0; i < 4; ++i) {
                f32x4 s0 = __builtin_amdgcn_mfma_f32_16x16x32_bf16(af[i], bk0, z4, 0, 0, 0);
                f32x4 s1 = __builtin_amdgcn_mfma_f32_16x16x32_bf16(af[i], bk1, z4, 0, 0, 0);
#pragma unroll
                for (int r = 0; r < 4; ++r) {
                    const float p0 = exp2f(s0[r] * C2);
                    const float p1 = exp2f(s1[r] * C2);
                    ps[i][r] += p0 + p1;
                    const int row = i * 16 + g * 4 + r;
                    Pw[row * 40 + c15]      = (unsigned short)((__float_as_uint(p0) + 0x8000u) >> 16);
                    Pw[row * 40 + 16 + c15] = (unsigned short)((__float_as_uint(p1) + 0x8000u) >> 16);
                }
            }
            // Ps is wave-private: no __syncthreads needed, but ds_write->ds_read needs lgkm drain
            asm volatile("s_waitcnt lgkmcnt(0)" ::: "memory");
            __builtin_amdgcn_sched_barrier(0);
            const short8 bv = *reinterpret_cast<const short8*>(&Vs[vrow][mb + g * 8]);
#pragma unroll
            for (int i = 0; i < 4; ++i) {
                const short8 pa = *reinterpret_cast<const short8*>(&Pw[(i * 16 + c15) * 40 + g * 8]);
                acc_o[i] = __builtin_amdgcn_mfma_f32_16x16x32_bf16(pa, bv, acc_o[i], 0, 0, 0);
            }
        }
    }

    // row-sums: reduce across the 16 lanes of each group (cols), then invert
#pragma unroll
    for (int i = 0; i < 4; ++i)
#pragma unroll
        for (int r = 0; r < 4; ++r) {
            float v = ps[i][r];
            v += __shfl_xor(v, 1);
            v += __shfl_xor(v, 2);
            v += __shfl_xor(v, 4);
            v += __shfl_xor(v, 8);
            ps[i][r] = 1.0f / v;
        }

    __syncthreads();   // all PV reads of Ps done before Ot overwrite
    // transpose out through LDS: Ot[d][68], lane holds col d = c15, rows q = i*16+g*4+r
    unsigned short* Ot = Pw;
    if (c15 < 12) {
#pragma unroll
        for (int i = 0; i < 4; ++i) {
            const unsigned int w0 = (unsigned int)f2bf(acc_o[i][0] * ps[i][0]) |
                                    ((unsigned int)f2bf(acc_o[i][1] * ps[i][1]) << 16);
            const unsigned int w1 = (unsigned int)f2bf(acc_o[i][2] * ps[i][2]) |
                                    ((unsigned int)f2bf(acc_o[i][3] * ps[i][3]) << 16);
            uint2v u; u[0] = w0; u[1] = w1;
            *reinterpret_cast<uint2v*>(&Ot[c15 * 68 + i * 16 + g * 4]) = u;
        }
    }
    __syncthreads();
    // coalesced-ish store: thread t <-> q-row lane of wave w; n = n0 + t
    unsigned int rr[6];
#pragma unroll
    for (int dp = 0; dp < 6; ++dp)
        rr[dp] = (unsigned int)Ot[(2 * dp) * 68 + lane] | ((unsigned int)Ot[(2 * dp + 1) * 68 + lane] << 16);
    unsigned short* dst = fused2 + ((size_t)b * HWN + n0 + t) * KTOT + coff + h * HD;
#pragma unroll
    for (int q = 0; q < 3; ++q) {
        uint2v u; u[0] = rr[2 * q]; u[1] = rr[2 * q + 1];
        *reinterpret_cast<uint2v*>(&dst[q * 4]) = u;
    }
}

extern "C" void kernel_launch(void* const* d_in, const int* in_sizes, int n_in,
                              void* d_out, int out_size, void* d_ws, size_t ws_size,
                              hipStream_t stream) {
    (void)in_sizes; (void)n_in; (void)out_size; (void)ws_size;
    const float* x   = (const float*)d_in[0];
    const float* xbp = (const float*)d_in[1];
    const float* Wq  = (const float*)d_in[2];  const float* bq  = (const float*)d_in[3];
    const float* Wk  = (const float*)d_in[4];  const float* bk  = (const float*)d_in[5];
    const float* Wv  = (const float*)d_in[6];  const float* bv  = (const float*)d_in[7];
    const float* Wqb = (const float*)d_in[8];  const float* bqb = (const float*)d_in[9];
    const float* Wkb = (const float*)d_in[10]; const float* bkb = (const float*)d_in[11];
    const float* Wvb = (const float*)d_in[12]; const float* bvb = (const float*)d_in[13];
    const float* Wo  = (const float*)d_in[14]; const float* bo  = (const float*)d_in[15];
    float* out = (float*)d_out;

    char* ws = (char*)d_ws;
    size_t off = 0;
    auto alloc = [&](size_t bytes) -> void* {
        void* p = ws + off;
        off = (off + bytes + 255) & ~(size_t)255;
        return p;
    };
    unsigned short* wbf[6];
    for (int i = 0; i < 6; ++i) wbf[i] = (unsigned short*)alloc((size_t)EMBED * EMBED * 2);
    unsigned short* wo2 = (unsigned short*)alloc((size_t)HIDDEN * KTOT * 2);
    unsigned short* qkv[6];
    for (int i = 0; i < 6; ++i) qkv[i] = (unsigned short*)alloc((size_t)BB * EMBED * HWN * 2);
    unsigned short* fused2 = (unsigned short*)alloc((size_t)BB * HWN * KTOT * 2);

    // 1) weights -> bf16 (Wo duplicated into Wo2)
    WConv wc;
    const float* wsrc[7] = {Wq, Wk, Wv, Wqb, Wkb, Wvb, Wo};
    unsigned short* wdst[7] = {wbf[0], wbf[1], wbf[2], wbf[3], wbf[4], wbf[5], wo2};
    int acc4 = 0;
    for (int i = 0; i < 7; ++i) {
        const int n = (i < 6) ? EMBED * EMBED : HIDDEN * 768;
        wc.src[i] = wsrc[i];
        wc.dst[i] = wdst[i];
        wc.start[i] = acc4;
        acc4 += n / 4;
    }
    wc.start[7] = acc4;
    k_bf16_all<<<(acc4 + 255) / 256, 256, 0, stream>>>(wc);

    // 2) x, x_bpf -> token-major bf16 into fused2 cols 768..1535
    k_transpose<<<dim3(EMBED / 32, HWN / 32, 16), 256, 0, stream>>>(x, xbp, fused2);

    // 3) six QKV projections (B read from fused2's xt region)
    QkvTable tab;
    tab.W[0] = wbf[0]; tab.W[1] = wbf[1]; tab.W[2] = wbf[2];
    tab.W[3] = wbf[3]; tab.W[4] = wbf[4]; tab.W[5] = wbf[5];
    tab.bias[0] = bq; tab.bias[1] = bk; tab.bias[2] = bv;
    tab.bias[3] = bqb; tab.bias[4] = bkb; tab.bias[5] = bvb;
    tab.fused2 = fused2;
    for (int i = 0; i < 6; ++i) tab.out[i] = qkv[i];
    k_gemm_qkv<<<dim3(EMBED / 64, HWN / 64, BB * 6), 256, 0, stream>>>(tab);

    // 4) MFMA attention -> fused2 cols 0..767 (residual folded into final GEMM)
    k_attn_mfma<<<dim3(2048), 256, 0, stream>>>(qkv[0], qkv[1], qkv[2], qkv[3], qkv[4], qkv[5],
                                                fused2);

    // 5) out = Wo2 . fused2 + bo   (K=1536 folds the residual)
    k_gemm_out<<<dim3(HIDDEN / 64, HWN / 64, BB), 256, 0, stream>>>(wo2, fused2, bo, out);
}

// Round 6
// 213.721 us; speedup vs baseline: 2.2603x; 1.3445x over previous
//
#include <hip/hip_runtime.h>
#include <hip/hip_bf16.h>

#define BB 8
#define EMBED 384
#define NH 32
#define HD 12
#define HWN 1024
#define HIDDEN 512
#define KTOT 1536
#define SCALE 0.28867513459481287f

typedef __attribute__((ext_vector_type(8))) unsigned short ushort8;
typedef __attribute__((ext_vector_type(8))) short short8;
typedef __attribute__((ext_vector_type(4))) float f32x4;
typedef __attribute__((ext_vector_type(4))) unsigned short ushort4v;
typedef __attribute__((ext_vector_type(2))) unsigned int uint2v;

static __device__ __forceinline__ float bf2f(unsigned short u) {
    return __uint_as_float(((unsigned int)u) << 16);
}
static __device__ __forceinline__ unsigned short f2bf(float f) {
    unsigned int u = __float_as_uint(f);
    u = u + 0x7FFFu + ((u >> 16) & 1u);   // RNE
    return (unsigned short)(u >> 16);
}
static __device__ __forceinline__ unsigned int cvt_pk_bf16(float lo, float hi) {
    unsigned int r;
    asm("v_cvt_pk_bf16_f32 %0, %1, %2" : "=v"(r) : "v"(lo), "v"(hi));
    return r;
}

// ---------------- f32 -> bf16 weights; Wo duplicated into Wo2[512][1536] ----------------
struct WConv {
    const float* src[7];
    unsigned short* dst[7];
    int start[8];   // prefix over vec4 counts
};

__global__ __launch_bounds__(256) void k_bf16_all(WConv wc) {
    int i = blockIdx.x * 256 + threadIdx.x;
    if (i >= wc.start[7]) return;
    int p = 0;
#pragma unroll
    for (int j = 1; j < 7; ++j) p += (i >= wc.start[j]);
    const int e = i - wc.start[p];
    const f32x4 v = reinterpret_cast<const f32x4*>(wc.src[p])[e];
    ushort4v o;
#pragma unroll
    for (int j = 0; j < 4; ++j) o[j] = f2bf(v[j]);
    if (p == 6) {
        const int row = e / 192, cc = e % 192;
        ushort4v* d = reinterpret_cast<ushort4v*>(wc.dst[6]);
        d[row * 384 + cc] = o;
        d[row * 384 + 192 + cc] = o;
    } else {
        reinterpret_cast<ushort4v*>(wc.dst[p])[e] = o;
    }
}

// ---------------- transpose x (B,C,HW) f32 -> fused2[b][n][768 + s*384 + c] bf16 ----------------
__global__ __launch_bounds__(256) void k_transpose(const float* __restrict__ x0, const float* __restrict__ x1,
                                                   unsigned short* __restrict__ fused2) {
    __shared__ float tile[32][33];
    const int z = blockIdx.z;
    const int s = z >> 3, b = z & 7;
    const float* src = (s ? x1 : x0) + (size_t)b * EMBED * HWN;
    unsigned short* dst = fused2 + (size_t)b * HWN * KTOT + 768 + s * 384;
    const int c0 = blockIdx.x * 32;
    const int n0 = blockIdx.y * 32;
    const int tc = threadIdx.x & 31;
    const int tr = threadIdx.x >> 5;
#pragma unroll
    for (int p = 0; p < 4; ++p) {
        int r = tr + p * 8;
        tile[r][tc] = src[(size_t)(c0 + r) * HWN + n0 + tc];
    }
    __syncthreads();
#pragma unroll
    for (int p = 0; p < 4; ++p) {
        int r = tr + p * 8;
        dst[(size_t)(n0 + r) * KTOT + c0 + tc] = f2bf(tile[tc][r]);
    }
}

// ---------------- bf16 MFMA GEMM: out[o][n] = sum_k A[o][k]*Bt[n][k] + bias[o] ----------------
template <bool F32OUT>
static __device__ __forceinline__ void gemm_core(const unsigned short* __restrict__ A, int lda,
                                                 const unsigned short* __restrict__ Bt, int ldb,
                                                 const float* __restrict__ bias,
                                                 unsigned short* __restrict__ outBf,
                                                 float* __restrict__ outF,
                                                 int K, int bx, int by) {
    __shared__ unsigned short As[64][72];
    __shared__ unsigned short Bs[64][72];
    const int t = threadIdx.x;
    const int lane = t & 63;
    const int wid = t >> 6;
    const int wr = wid >> 1, wc = wid & 1;
    const int o0 = bx * 64, n0 = by * 64;
    const int lrow = t >> 2;
    const int lseg = t & 3;

    f32x4 acc[2][2] = {};

    for (int k0 = 0; k0 < K; k0 += 64) {
        const ushort8* ga = reinterpret_cast<const ushort8*>(A + (size_t)(o0 + lrow) * lda + k0 + lseg * 16);
        const ushort8* gb = reinterpret_cast<const ushort8*>(Bt + (size_t)(n0 + lrow) * ldb + k0 + lseg * 16);
        ushort8 a0 = ga[0], a1 = ga[1];
        ushort8 b0 = gb[0], b1 = gb[1];
        *reinterpret_cast<ushort8*>(&As[lrow][lseg * 16]) = a0;
        *reinterpret_cast<ushort8*>(&As[lrow][lseg * 16 + 8]) = a1;
        *reinterpret_cast<ushort8*>(&Bs[lrow][lseg * 16]) = b0;
        *reinterpret_cast<ushort8*>(&Bs[lrow][lseg * 16 + 8]) = b1;
        __syncthreads();
#pragma unroll
        for (int kk = 0; kk < 2; ++kk) {
            const int ko = kk * 32 + ((lane >> 4) << 3);
            short8 af[2], bfv[2];
            af[0]  = *reinterpret_cast<const short8*>(&As[wr * 32 + (lane & 15)][ko]);
            af[1]  = *reinterpret_cast<const short8*>(&As[wr * 32 + 16 + (lane & 15)][ko]);
            bfv[0] = *reinterpret_cast<const short8*>(&Bs[wc * 32 + (lane & 15)][ko]);
            bfv[1] = *reinterpret_cast<const short8*>(&Bs[wc * 32 + 16 + (lane & 15)][ko]);
#pragma unroll
            for (int i = 0; i < 2; ++i)
#pragma unroll
                for (int j = 0; j < 2; ++j)
                    acc[i][j] = __builtin_amdgcn_mfma_f32_16x16x32_bf16(af[i], bfv[j], acc[i][j], 0, 0, 0);
        }
        __syncthreads();
    }
#pragma unroll
    for (int i = 0; i < 2; ++i) {
#pragma unroll
        for (int j = 0; j < 2; ++j) {
            const int ob = o0 + wr * 32 + i * 16 + ((lane >> 4) << 2);
            const int n  = n0 + wc * 32 + j * 16 + (lane & 15);
#pragma unroll
            for (int r = 0; r < 4; ++r) {
                const int o = ob + r;
                float v = acc[i][j][r] + bias[o];
                if constexpr (F32OUT) outF[(size_t)o * HWN + n] = v;
                else                  outBf[(size_t)o * HWN + n] = f2bf(v);
            }
        }
    }
}

struct QkvTable {
    const unsigned short* W[6];
    const float* bias[6];
    const unsigned short* fused2;
    unsigned short* out[6];
};

__global__ __launch_bounds__(256) void k_gemm_qkv(QkvTable tab) {
    const int z = blockIdx.z;
    const int b = z / 6, p = z % 6;
    const unsigned short* Bt = tab.fused2 + (size_t)b * HWN * KTOT + 768 + (p / 3) * 384;
    gemm_core<false>(tab.W[p], EMBED, Bt, KTOT, tab.bias[p],
                     tab.out[p] + (size_t)b * EMBED * HWN, nullptr,
                     EMBED, blockIdx.x, blockIdx.y);
}

__global__ __launch_bounds__(256) void k_gemm_out(const unsigned short* __restrict__ Wo2,
                                                  const unsigned short* __restrict__ fused2,
                                                  const float* __restrict__ bo,
                                                  float* __restrict__ out) {
    const int b = blockIdx.z;
    gemm_core<true>(Wo2, KTOT, fused2 + (size_t)b * HWN * KTOT, KTOT, bo,
                    nullptr, out + (size_t)b * HIDDEN * HWN,
                    KTOT, blockIdx.x, blockIdx.y);
}

// ---------------- MFMA flash attention v2: swapped QK^T, packed P, conflict-free staging ----------------
// grid 2048 = instance(512) x qtile(4, 256 q-rows); 256 threads = 4 waves, wave w owns q [w*64, w*64+64).
__global__ __launch_bounds__(256) void k_attn_mfma(const unsigned short* __restrict__ qc,
                                                   const unsigned short* __restrict__ kc,
                                                   const unsigned short* __restrict__ vc,
                                                   const unsigned short* __restrict__ qcb,
                                                   const unsigned short* __restrict__ kcb,
                                                   const unsigned short* __restrict__ vcb,
                                                   unsigned short* __restrict__ fused2) {
    __shared__ unsigned short Ks[512][16];       // [m][d], d 12..15 zero
    __shared__ unsigned short Vs[12][520];       // [d][m]
    __shared__ unsigned short Ps[4][4][16][40];  // per-wave P: [i-tile][q][20 dw = 16 m-dw + pad]

    const int bid = blockIdx.x;
    const int inst = bid >> 2, qt = bid & 3;
    const int branch = inst >> 8, b = (inst >> 5) & 7, h = inst & 31;
    const unsigned short* Qg = branch ? qc : qcb;
    const unsigned short* Kg = branch ? kcb : kc;
    const unsigned short* Vg = branch ? vcb : vc;
    const int coff = branch ? 384 : 0;
    const size_t base = ((size_t)b * EMBED + h * HD) * HWN;
    const int t = threadIdx.x;
    const int lane = t & 63, w = t >> 6;
    const int c15 = lane & 15, g = lane >> 4;
    const int n0 = qt * 256;
    const bool ldA = lane < 32;
    const float C2 = SCALE * 1.4426950408889634f;

    // Q B-frags straight from global (once): lane c15 = q-col, k = d = g*8+j (zero for d>=12, g>=2)
    short8 qf[4];
#pragma unroll
    for (int i = 0; i < 4; ++i) {
        short8 v = {};
        if (g < 2) {
#pragma unroll
            for (int j = 0; j < 8; ++j) {
                const int d = g * 8 + j;
                if (d < HD) v[j] = (short)Qg[base + (size_t)d * HWN + n0 + w * 64 + i * 16 + c15];
            }
        }
        qf[i] = v;
    }

    f32x4 acc_o[4] = {};
    float psum[4] = {0.f, 0.f, 0.f, 0.f};
    const f32x4 z4 = {0.f, 0.f, 0.f, 0.f};

    for (int phase = 0; phase < 2; ++phase) {
        const int m0 = phase << 9;
        __syncthreads();   // prior-phase reads done
        // stage K [m][16]: lane -> (d = t&15, m = t>>4) : conflict-free LDS writes
        {
            const int d = t & 15;
            const int mr = t >> 4;
            const size_t gb = base + (size_t)d * HWN + m0;
#pragma unroll
            for (int it = 0; it < 32; ++it) {
                const int m = mr + it * 16;
                Ks[m][d] = (d < HD) ? Kg[gb + m] : (unsigned short)0;
            }
        }
        // stage V [d][512] vectorized
#pragma unroll
        for (int i = 0; i < 3; ++i) {
            const int idx = i * 256 + t;
            const int d = idx >> 6, m8 = (idx & 63) << 3;
            *reinterpret_cast<ushort8*>(&Vs[d][m8]) =
                *reinterpret_cast<const ushort8*>(&Vg[base + (size_t)d * HWN + m0 + m8]);
        }
        __syncthreads();

        for (int mc = 0; mc < 16; ++mc) {
            const int mb = mc << 5;
            short8 kf0 = {}, kf1 = {};
            if (ldA) {
                kf0 = *reinterpret_cast<const short8*>(&Ks[mb + c15][g * 8]);
                kf1 = *reinterpret_cast<const short8*>(&Ks[mb + 16 + c15][g * 8]);
            }
#pragma unroll
            for (int i = 0; i < 4; ++i) {
                // swapped: D[m-row][q-col]; lane: q = c15, m = g*4+r (+16 for s1)
                f32x4 s0 = __builtin_amdgcn_mfma_f32_16x16x32_bf16(kf0, qf[i], z4, 0, 0, 0);
                f32x4 s1 = __builtin_amdgcn_mfma_f32_16x16x32_bf16(kf1, qf[i], z4, 0, 0, 0);
                float p0[4], p1[4];
#pragma unroll
                for (int r = 0; r < 4; ++r) {
                    p0[r] = __builtin_amdgcn_exp2f(s0[r] * C2);
                    p1[r] = __builtin_amdgcn_exp2f(s1[r] * C2);
                }
                psum[i] += ((p0[0] + p0[1]) + (p0[2] + p0[3])) + ((p1[0] + p1[1]) + (p1[2] + p1[3]));
                uint2v u0, u1;
                u0[0] = cvt_pk_bf16(p0[0], p0[1]);   // m-dwords 2g, 2g+1
                u0[1] = cvt_pk_bf16(p0[2], p0[3]);
                u1[0] = cvt_pk_bf16(p1[0], p1[1]);   // m-dwords 8+2g, 8+2g+1
                u1[1] = cvt_pk_bf16(p1[2], p1[3]);
                *reinterpret_cast<uint2v*>(&Ps[w][i][c15][g * 4]) = u0;
                *reinterpret_cast<uint2v*>(&Ps[w][i][c15][16 + g * 4]) = u1;
            }
            asm volatile("s_waitcnt lgkmcnt(0)" ::: "memory");
            __builtin_amdgcn_sched_barrier(0);
            const int vrow = (c15 < HD) ? c15 : (HD - 1);
            const short8 bv = *reinterpret_cast<const short8*>(&Vs[vrow][mb + g * 8]);
#pragma unroll
            for (int i = 0; i < 4; ++i) {
                const short8 pa = *reinterpret_cast<const short8*>(&Ps[w][i][c15][g * 8]);
                acc_o[i] = __builtin_amdgcn_mfma_f32_16x16x32_bf16(pa, bv, acc_o[i], 0, 0, 0);
            }
        }
    }

    // row-sums: psum[i] partial per lane (q = c15); sum across the 4 g-groups
    float invq[4][4];
#pragma unroll
    for (int i = 0; i < 4; ++i) {
        float v = psum[i];
        v += __shfl_xor(v, 16);
        v += __shfl_xor(v, 32);
        const float inv = 1.0f / v;
        // acc_o rows are q = g*4+r: pull inv for that q from lane q (c15 = q, g = 0)
#pragma unroll
        for (int r = 0; r < 4; ++r) invq[i][r] = __shfl(inv, g * 4 + r);
    }

    __syncthreads();   // all PV reads of Ps done before Ot overwrite
    unsigned short* Ot = &Ps[w][0][0][0];   // [12 d][68] per wave
    if (c15 < HD) {
#pragma unroll
        for (int i = 0; i < 4; ++i) {
            const unsigned int w0 = (unsigned int)f2bf(acc_o[i][0] * invq[i][0]) |
                                    ((unsigned int)f2bf(acc_o[i][1] * invq[i][1]) << 16);
            const unsigned int w1 = (unsigned int)f2bf(acc_o[i][2] * invq[i][2]) |
                                    ((unsigned int)f2bf(acc_o[i][3] * invq[i][3]) << 16);
            uint2v u; u[0] = w0; u[1] = w1;
            *reinterpret_cast<uint2v*>(&Ot[c15 * 68 + i * 16 + g * 4]) = u;
        }
    }
    __syncthreads();
    unsigned int rr[6];
#pragma unroll
    for (int dp = 0; dp < 6; ++dp)
        rr[dp] = (unsigned int)Ot[(2 * dp) * 68 + lane] | ((unsigned int)Ot[(2 * dp + 1) * 68 + lane] << 16);
    unsigned short* dst = fused2 + ((size_t)b * HWN + n0 + t) * KTOT + coff + h * HD;
#pragma unroll
    for (int q = 0; q < 3; ++q) {
        uint2v u; u[0] = rr[2 * q]; u[1] = rr[2 * q + 1];
        *reinterpret_cast<uint2v*>(&dst[q * 4]) = u;
    }
}

extern "C" void kernel_launch(void* const* d_in, const int* in_sizes, int n_in,
                              void* d_out, int out_size, void* d_ws, size_t ws_size,
                              hipStream_t stream) {
    (void)in_sizes; (void)n_in; (void)out_size; (void)ws_size;
    const float* x   = (const float*)d_in[0];
    const float* xbp = (const float*)d_in[1];
    const float* Wq  = (const float*)d_in[2];  const float* bq  = (const float*)d_in[3];
    const float* Wk  = (const float*)d_in[4];  const float* bk  = (const float*)d_in[5];
    const float* Wv  = (const float*)d_in[6];  const float* bv  = (const float*)d_in[7];
    const float* Wqb = (const float*)d_in[8];  const float* bqb = (const float*)d_in[9];
    const float* Wkb = (const float*)d_in[10]; const float* bkb = (const float*)d_in[11];
    const float* Wvb = (const float*)d_in[12]; const float* bvb = (const float*)d_in[13];
    const float* Wo  = (const float*)d_in[14]; const float* bo  = (const float*)d_in[15];
    float* out = (float*)d_out;

    char* ws = (char*)d_ws;
    size_t off = 0;
    auto alloc = [&](size_t bytes) -> void* {
        void* p = ws + off;
        off = (off + bytes + 255) & ~(size_t)255;
        return p;
    };
    unsigned short* wbf[6];
    for (int i = 0; i < 6; ++i) wbf[i] = (unsigned short*)alloc((size_t)EMBED * EMBED * 2);
    unsigned short* wo2 = (unsigned short*)alloc((size_t)HIDDEN * KTOT * 2);
    unsigned short* qkv[6];
    for (int i = 0; i < 6; ++i) qkv[i] = (unsigned short*)alloc((size_t)BB * EMBED * HWN * 2);
    unsigned short* fused2 = (unsigned short*)alloc((size_t)BB * HWN * KTOT * 2);

    // 1) weights -> bf16 (Wo duplicated into Wo2)
    WConv wc;
    const float* wsrc[7] = {Wq, Wk, Wv, Wqb, Wkb, Wvb, Wo};
    unsigned short* wdst[7] = {wbf[0], wbf[1], wbf[2], wbf[3], wbf[4], wbf[5], wo2};
    int acc4 = 0;
    for (int i = 0; i < 7; ++i) {
        const int n = (i < 6) ? EMBED * EMBED : HIDDEN * 768;
        wc.src[i] = wsrc[i];
        wc.dst[i] = wdst[i];
        wc.start[i] = acc4;
        acc4 += n / 4;
    }
    wc.start[7] = acc4;
    k_bf16_all<<<(acc4 + 255) / 256, 256, 0, stream>>>(wc);

    // 2) x, x_bpf -> token-major bf16 into fused2 cols 768..1535
    k_transpose<<<dim3(EMBED / 32, HWN / 32, 16), 256, 0, stream>>>(x, xbp, fused2);

    // 3) six QKV projections
    QkvTable tab;
    tab.W[0] = wbf[0]; tab.W[1] = wbf[1]; tab.W[2] = wbf[2];
    tab.W[3] = wbf[3]; tab.W[4] = wbf[4]; tab.W[5] = wbf[5];
    tab.bias[0] = bq; tab.bias[1] = bk; tab.bias[2] = bv;
    tab.bias[3] = bqb; tab.bias[4] = bkb; tab.bias[5] = bvb;
    tab.fused2 = fused2;
    for (int i = 0; i < 6; ++i) tab.out[i] = qkv[i];
    k_gemm_qkv<<<dim3(EMBED / 64, HWN / 64, BB * 6), 256, 0, stream>>>(tab);

    // 4) MFMA attention -> fused2 cols 0..767
    k_attn_mfma<<<dim3(2048), 256, 0, stream>>>(qkv[0], qkv[1], qkv[2], qkv[3], qkv[4], qkv[5],
                                                fused2);

    // 5) out = Wo2 . fused2 + bo   (K=1536 folds the residual)
    k_gemm_out<<<dim3(HIDDEN / 64, HWN / 64, BB), 256, 0, stream>>>(wo2, fused2, bo, out);
}

// Round 7
// 193.084 us; speedup vs baseline: 2.5019x; 1.1069x over previous
//
#include <hip/hip_runtime.h>
#include <hip/hip_bf16.h>

#define BB 8
#define EMBED 384
#define NH 32
#define HD 12
#define HWN 1024
#define HIDDEN 512
#define KTOT 1536
#define SCALE 0.28867513459481287f

typedef __attribute__((ext_vector_type(8))) unsigned short ushort8;
typedef __attribute__((ext_vector_type(8))) short short8;
typedef __attribute__((ext_vector_type(4))) float f32x4;
typedef __attribute__((ext_vector_type(4))) unsigned short ushort4v;
typedef __attribute__((ext_vector_type(2))) unsigned int uint2v;

static __device__ __forceinline__ float bf2f(unsigned short u) {
    return __uint_as_float(((unsigned int)u) << 16);
}
static __device__ __forceinline__ unsigned short f2bf(float f) {
    unsigned int u = __float_as_uint(f);
    u = u + 0x7FFFu + ((u >> 16) & 1u);   // RNE
    return (unsigned short)(u >> 16);
}
static __device__ __forceinline__ unsigned int cvt_pk_bf16(float lo, float hi) {
    unsigned int r;
    asm("v_cvt_pk_bf16_f32 %0, %1, %2" : "=v"(r) : "v"(lo), "v"(hi));
    return r;
}

// ---------------- f32 -> bf16 weights; Wo duplicated into Wo2[512][1536] ----------------
struct WConv {
    const float* src[7];
    unsigned short* dst[7];
    int start[8];   // prefix over vec4 counts
};

__global__ __launch_bounds__(256) void k_bf16_all(WConv wc) {
    int i = blockIdx.x * 256 + threadIdx.x;
    if (i >= wc.start[7]) return;
    int p = 0;
#pragma unroll
    for (int j = 1; j < 7; ++j) p += (i >= wc.start[j]);
    const int e = i - wc.start[p];
    const f32x4 v = reinterpret_cast<const f32x4*>(wc.src[p])[e];
    ushort4v o;
#pragma unroll
    for (int j = 0; j < 4; ++j) o[j] = f2bf(v[j]);
    if (p == 6) {
        const int row = e / 192, cc = e % 192;
        ushort4v* d = reinterpret_cast<ushort4v*>(wc.dst[6]);
        d[row * 384 + cc] = o;
        d[row * 384 + 192 + cc] = o;
    } else {
        reinterpret_cast<ushort4v*>(wc.dst[p])[e] = o;
    }
}

// ---------------- transpose x (B,C,HW) f32 -> fused2[b][n][768 + s*384 + c] bf16 ----------------
__global__ __launch_bounds__(256) void k_transpose(const float* __restrict__ x0, const float* __restrict__ x1,
                                                   unsigned short* __restrict__ fused2) {
    __shared__ float tile[32][33];
    const int z = blockIdx.z;
    const int s = z >> 3, b = z & 7;
    const float* src = (s ? x1 : x0) + (size_t)b * EMBED * HWN;
    unsigned short* dst = fused2 + (size_t)b * HWN * KTOT + 768 + s * 384;
    const int c0 = blockIdx.x * 32;
    const int n0 = blockIdx.y * 32;
    const int tc = threadIdx.x & 31;
    const int tr = threadIdx.x >> 5;
#pragma unroll
    for (int p = 0; p < 4; ++p) {
        int r = tr + p * 8;
        tile[r][tc] = src[(size_t)(c0 + r) * HWN + n0 + tc];
    }
    __syncthreads();
#pragma unroll
    for (int p = 0; p < 4; ++p) {
        int r = tr + p * 8;
        dst[(size_t)(n0 + r) * KTOT + c0 + tc] = f2bf(tile[tc][r]);
    }
}

// ---------------- bf16 MFMA GEMM: out[o][n] = sum_k A[o][k]*Bt[n][k] + bias[o] ----------------
template <bool F32OUT>
static __device__ __forceinline__ void gemm_core(const unsigned short* __restrict__ A, int lda,
                                                 const unsigned short* __restrict__ Bt, int ldb,
                                                 const float* __restrict__ bias,
                                                 unsigned short* __restrict__ outBf,
                                                 float* __restrict__ outF,
                                                 int K, int bx, int by) {
    __shared__ unsigned short As[64][72];
    __shared__ unsigned short Bs[64][72];
    const int t = threadIdx.x;
    const int lane = t & 63;
    const int wid = t >> 6;
    const int wr = wid >> 1, wc = wid & 1;
    const int o0 = bx * 64, n0 = by * 64;
    const int lrow = t >> 2;
    const int lseg = t & 3;

    f32x4 acc[2][2] = {};

    for (int k0 = 0; k0 < K; k0 += 64) {
        const ushort8* ga = reinterpret_cast<const ushort8*>(A + (size_t)(o0 + lrow) * lda + k0 + lseg * 16);
        const ushort8* gb = reinterpret_cast<const ushort8*>(Bt + (size_t)(n0 + lrow) * ldb + k0 + lseg * 16);
        ushort8 a0 = ga[0], a1 = ga[1];
        ushort8 b0 = gb[0], b1 = gb[1];
        *reinterpret_cast<ushort8*>(&As[lrow][lseg * 16]) = a0;
        *reinterpret_cast<ushort8*>(&As[lrow][lseg * 16 + 8]) = a1;
        *reinterpret_cast<ushort8*>(&Bs[lrow][lseg * 16]) = b0;
        *reinterpret_cast<ushort8*>(&Bs[lrow][lseg * 16 + 8]) = b1;
        __syncthreads();
#pragma unroll
        for (int kk = 0; kk < 2; ++kk) {
            const int ko = kk * 32 + ((lane >> 4) << 3);
            short8 af[2], bfv[2];
            af[0]  = *reinterpret_cast<const short8*>(&As[wr * 32 + (lane & 15)][ko]);
            af[1]  = *reinterpret_cast<const short8*>(&As[wr * 32 + 16 + (lane & 15)][ko]);
            bfv[0] = *reinterpret_cast<const short8*>(&Bs[wc * 32 + (lane & 15)][ko]);
            bfv[1] = *reinterpret_cast<const short8*>(&Bs[wc * 32 + 16 + (lane & 15)][ko]);
#pragma unroll
            for (int i = 0; i < 2; ++i)
#pragma unroll
                for (int j = 0; j < 2; ++j)
                    acc[i][j] = __builtin_amdgcn_mfma_f32_16x16x32_bf16(af[i], bfv[j], acc[i][j], 0, 0, 0);
        }
        __syncthreads();
    }
#pragma unroll
    for (int i = 0; i < 2; ++i) {
#pragma unroll
        for (int j = 0; j < 2; ++j) {
            const int ob = o0 + wr * 32 + i * 16 + ((lane >> 4) << 2);
            const int n  = n0 + wc * 32 + j * 16 + (lane & 15);
#pragma unroll
            for (int r = 0; r < 4; ++r) {
                const int o = ob + r;
                float v = acc[i][j][r] + bias[o];
                if constexpr (F32OUT) outF[(size_t)o * HWN + n] = v;
                else                  outBf[(size_t)o * HWN + n] = f2bf(v);
            }
        }
    }
}

struct QkvTable {
    const unsigned short* W[6];
    const float* bias[6];
    const unsigned short* fused2;
    unsigned short* out[6];
};

__global__ __launch_bounds__(256) void k_gemm_qkv(QkvTable tab) {
    const int z = blockIdx.z;
    const int b = z / 6, p = z % 6;
    const unsigned short* Bt = tab.fused2 + (size_t)b * HWN * KTOT + 768 + (p / 3) * 384;
    gemm_core<false>(tab.W[p], EMBED, Bt, KTOT, tab.bias[p],
                     tab.out[p] + (size_t)b * EMBED * HWN, nullptr,
                     EMBED, blockIdx.x, blockIdx.y);
}

__global__ __launch_bounds__(256) void k_gemm_out(const unsigned short* __restrict__ Wo2,
                                                  const unsigned short* __restrict__ fused2,
                                                  const float* __restrict__ bo,
                                                  float* __restrict__ out) {
    const int b = blockIdx.z;
    gemm_core<true>(Wo2, KTOT, fused2 + (size_t)b * HWN * KTOT, KTOT, bo,
                    nullptr, out + (size_t)b * HIDDEN * HWN,
                    KTOT, blockIdx.x, blockIdx.y);
}

// ---------------- MFMA flash attention v3 ----------------
// Changes vs v2: Ks [512][18] (36B rows, 9 dw: coprime-32 bank spread; read2_b32 frags),
// coalesced K gather (wave w owns d-rows 4w..4w+3), C2 folded into Q frags,
// row-sums via 13th all-ones V row (PV MFMA column d=12 = sum of P).
__global__ __launch_bounds__(256) void k_attn_mfma(const unsigned short* __restrict__ qc,
                                                   const unsigned short* __restrict__ kc,
                                                   const unsigned short* __restrict__ vc,
                                                   const unsigned short* __restrict__ qcb,
                                                   const unsigned short* __restrict__ kcb,
                                                   const unsigned short* __restrict__ vcb,
                                                   unsigned short* __restrict__ fused2) {
    __shared__ unsigned short Ks[512][18];       // [m][d 0..15 + 2 pad], 36B rows
    __shared__ unsigned short Vs[13][520];       // [d][m], row 12 = ones
    __shared__ unsigned short Ps[4][4][16][40];  // per-wave P: [i-tile][q][16 m-dw + pad]

    const int bid = blockIdx.x;
    const int inst = bid >> 2, qt = bid & 3;
    const int branch = inst >> 8, b = (inst >> 5) & 7, h = inst & 31;
    const unsigned short* Qg = branch ? qc : qcb;
    const unsigned short* Kg = branch ? kcb : kc;
    const unsigned short* Vg = branch ? vcb : vc;
    const int coff = branch ? 384 : 0;
    const size_t base = ((size_t)b * EMBED + h * HD) * HWN;
    const int t = threadIdx.x;
    const int lane = t & 63, w = t >> 6;
    const int c15 = lane & 15, g = lane >> 4;
    const int n0 = qt * 256;
    const bool ldA = lane < 32;
    const float C2 = SCALE * 1.4426950408889634f;

    // Q B-frags from global, pre-scaled by C2 (bf16 re-round: one extra 0.4% rounding)
    short8 qf[4];
#pragma unroll
    for (int i = 0; i < 4; ++i) {
        short8 v = {};
        if (g < 2) {
#pragma unroll
            for (int j = 0; j < 8; ++j) {
                const int d = g * 8 + j;
                if (d < HD)
                    v[j] = (short)f2bf(bf2f(Qg[base + (size_t)d * HWN + n0 + w * 64 + i * 16 + c15]) * C2);
            }
        }
        qf[i] = v;
    }

    f32x4 acc_o[4] = {};
    const f32x4 z4 = {0.f, 0.f, 0.f, 0.f};

    for (int phase = 0; phase < 2; ++phase) {
        const int m0 = phase << 9;
        __syncthreads();   // prior-phase reads done
        // --- stage K: wave w owns d-rows 4w..4w+3 (w=3 -> zeros). 128B-coalesced gathers.
        {
            const size_t kb = base + (size_t)(4 * w) * HWN + m0;
#pragma unroll
            for (int it = 0; it < 8; ++it) {
                const int m = it * 64 + lane;
                unsigned int da = 0, db = 0;
                if (w < 3) {
                    da = (unsigned int)Kg[kb + m] | ((unsigned int)Kg[kb + HWN + m] << 16);
                    db = (unsigned int)Kg[kb + 2 * HWN + m] | ((unsigned int)Kg[kb + 3 * HWN + m] << 16);
                }
                unsigned int* p = reinterpret_cast<unsigned int*>(&Ks[m][w * 4]);
                p[0] = da;
                p[1] = db;
            }
        }
        // --- stage V [d][512] vectorized + ones row (d = 12)
#pragma unroll
        for (int i = 0; i < 4; ++i) {
            const int idx = i * 256 + t;
            if (idx < 832) {
                const int d = idx >> 6, m8 = (idx & 63) << 3;
                ushort8 v;
                if (d < HD) {
                    v = *reinterpret_cast<const ushort8*>(&Vg[base + (size_t)d * HWN + m0 + m8]);
                } else {
#pragma unroll
                    for (int j = 0; j < 8; ++j) v[j] = 0x3F80;   // 1.0 bf16
                }
                *reinterpret_cast<ushort8*>(&Vs[d][m8]) = v;
            }
        }
        __syncthreads();

        for (int mc = 0; mc < 16; ++mc) {
            const int mb = mc << 5;
            short8 kf0 = {}, kf1 = {};
            if (ldA) {
                union { short8 v; unsigned int u[4]; } a, bb;
                const unsigned int* p0 = reinterpret_cast<const unsigned int*>(&Ks[mb + c15][g * 8]);
                a.u[0] = p0[0]; a.u[1] = p0[1]; a.u[2] = p0[2]; a.u[3] = p0[3];
                const unsigned int* p1 = reinterpret_cast<const unsigned int*>(&Ks[mb + 16 + c15][g * 8]);
                bb.u[0] = p1[0]; bb.u[1] = p1[1]; bb.u[2] = p1[2]; bb.u[3] = p1[3];
                kf0 = a.v; kf1 = bb.v;
            }
#pragma unroll
            for (int i = 0; i < 4; ++i) {
                // swapped QK^T: D[m-row][q-col]; lane: q = c15, m = g*4+r (+16 for s1)
                f32x4 s0 = __builtin_amdgcn_mfma_f32_16x16x32_bf16(kf0, qf[i], z4, 0, 0, 0);
                f32x4 s1 = __builtin_amdgcn_mfma_f32_16x16x32_bf16(kf1, qf[i], z4, 0, 0, 0);
                float p0[4], p1[4];
#pragma unroll
                for (int r = 0; r < 4; ++r) {
                    p0[r] = __builtin_amdgcn_exp2f(s0[r]);
                    p1[r] = __builtin_amdgcn_exp2f(s1[r]);
                }
                uint2v u0, u1;
                u0[0] = cvt_pk_bf16(p0[0], p0[1]);
                u0[1] = cvt_pk_bf16(p0[2], p0[3]);
                u1[0] = cvt_pk_bf16(p1[0], p1[1]);
                u1[1] = cvt_pk_bf16(p1[2], p1[3]);
                *reinterpret_cast<uint2v*>(&Ps[w][i][c15][g * 4]) = u0;
                *reinterpret_cast<uint2v*>(&Ps[w][i][c15][16 + g * 4]) = u1;
            }
            asm volatile("s_waitcnt lgkmcnt(0)" ::: "memory");
            __builtin_amdgcn_sched_barrier(0);
            const int vrow = (c15 < 12) ? c15 : 12;   // 12 = ones row -> col 12 = row-sum
            const short8 bv = *reinterpret_cast<const short8*>(&Vs[vrow][mb + g * 8]);
#pragma unroll
            for (int i = 0; i < 4; ++i) {
                const short8 pa = *reinterpret_cast<const short8*>(&Ps[w][i][c15][g * 8]);
                acc_o[i] = __builtin_amdgcn_mfma_f32_16x16x32_bf16(pa, bv, acc_o[i], 0, 0, 0);
            }
        }
    }

    // inverse row-sums from the ones-column (lane c15 = 12 of each g-group)
    float invq[4][4];
#pragma unroll
    for (int i = 0; i < 4; ++i)
#pragma unroll
        for (int r = 0; r < 4; ++r)
            invq[i][r] = 1.0f / __shfl(acc_o[i][r], (lane & 48) | 12);

    __syncthreads();   // all PV reads of Ps done before Ot overwrite
    unsigned short* Ot = &Ps[w][0][0][0];   // [12 d][68] per wave
    if (c15 < HD) {
#pragma unroll
        for (int i = 0; i < 4; ++i) {
            const unsigned int w0 = (unsigned int)f2bf(acc_o[i][0] * invq[i][0]) |
                                    ((unsigned int)f2bf(acc_o[i][1] * invq[i][1]) << 16);
            const unsigned int w1 = (unsigned int)f2bf(acc_o[i][2] * invq[i][2]) |
                                    ((unsigned int)f2bf(acc_o[i][3] * invq[i][3]) << 16);
            uint2v u; u[0] = w0; u[1] = w1;
            *reinterpret_cast<uint2v*>(&Ot[c15 * 68 + i * 16 + g * 4]) = u;
        }
    }
    __syncthreads();
    unsigned int rr[6];
#pragma unroll
    for (int dp = 0; dp < 6; ++dp)
        rr[dp] = (unsigned int)Ot[(2 * dp) * 68 + lane] | ((unsigned int)Ot[(2 * dp + 1) * 68 + lane] << 16);
    unsigned short* dst = fused2 + ((size_t)b * HWN + n0 + t) * KTOT + coff + h * HD;
#pragma unroll
    for (int q = 0; q < 3; ++q) {
        uint2v u; u[0] = rr[2 * q]; u[1] = rr[2 * q + 1];
        *reinterpret_cast<uint2v*>(&dst[q * 4]) = u;
    }
}

extern "C" void kernel_launch(void* const* d_in, const int* in_sizes, int n_in,
                              void* d_out, int out_size, void* d_ws, size_t ws_size,
                              hipStream_t stream) {
    (void)in_sizes; (void)n_in; (void)out_size; (void)ws_size;
    const float* x   = (const float*)d_in[0];
    const float* xbp = (const float*)d_in[1];
    const float* Wq  = (const float*)d_in[2];  const float* bq  = (const float*)d_in[3];
    const float* Wk  = (const float*)d_in[4];  const float* bk  = (const float*)d_in[5];
    const float* Wv  = (const float*)d_in[6];  const float* bv  = (const float*)d_in[7];
    const float* Wqb = (const float*)d_in[8];  const float* bqb = (const float*)d_in[9];
    const float* Wkb = (const float*)d_in[10]; const float* bkb = (const float*)d_in[11];
    const float* Wvb = (const float*)d_in[12]; const float* bvb = (const float*)d_in[13];
    const float* Wo  = (const float*)d_in[14]; const float* bo  = (const float*)d_in[15];
    float* out = (float*)d_out;

    char* ws = (char*)d_ws;
    size_t off = 0;
    auto alloc = [&](size_t bytes) -> void* {
        void* p = ws + off;
        off = (off + bytes + 255) & ~(size_t)255;
        return p;
    };
    unsigned short* wbf[6];
    for (int i = 0; i < 6; ++i) wbf[i] = (unsigned short*)alloc((size_t)EMBED * EMBED * 2);
    unsigned short* wo2 = (unsigned short*)alloc((size_t)HIDDEN * KTOT * 2);
    unsigned short* qkv[6];
    for (int i = 0; i < 6; ++i) qkv[i] = (unsigned short*)alloc((size_t)BB * EMBED * HWN * 2);
    unsigned short* fused2 = (unsigned short*)alloc((size_t)BB * HWN * KTOT * 2);

    // 1) weights -> bf16 (Wo duplicated into Wo2)
    WConv wc;
    const float* wsrc[7] = {Wq, Wk, Wv, Wqb, Wkb, Wvb, Wo};
    unsigned short* wdst[7] = {wbf[0], wbf[1], wbf[2], wbf[3], wbf[4], wbf[5], wo2};
    int acc4 = 0;
    for (int i = 0; i < 7; ++i) {
        const int n = (i < 6) ? EMBED * EMBED : HIDDEN * 768;
        wc.src[i] = wsrc[i];
        wc.dst[i] = wdst[i];
        wc.start[i] = acc4;
        acc4 += n / 4;
    }
    wc.start[7] = acc4;
    k_bf16_all<<<(acc4 + 255) / 256, 256, 0, stream>>>(wc);

    // 2) x, x_bpf -> token-major bf16 into fused2 cols 768..1535
    k_transpose<<<dim3(EMBED / 32, HWN / 32, 16), 256, 0, stream>>>(x, xbp, fused2);

    // 3) six QKV projections
    QkvTable tab;
    tab.W[0] = wbf[0]; tab.W[1] = wbf[1]; tab.W[2] = wbf[2];
    tab.W[3] = wbf[3]; tab.W[4] = wbf[4]; tab.W[5] = wbf[5];
    tab.bias[0] = bq; tab.bias[1] = bk; tab.bias[2] = bv;
    tab.bias[3] = bqb; tab.bias[4] = bkb; tab.bias[5] = bvb;
    tab.fused2 = fused2;
    for (int i = 0; i < 6; ++i) tab.out[i] = qkv[i];
    k_gemm_qkv<<<dim3(EMBED / 64, HWN / 64, BB * 6), 256, 0, stream>>>(tab);

    // 4) MFMA attention -> fused2 cols 0..767
    k_attn_mfma<<<dim3(2048), 256, 0, stream>>>(qkv[0], qkv[1], qkv[2], qkv[3], qkv[4], qkv[5],
                                                fused2);

    // 5) out = Wo2 . fused2 + bo   (K=1536 folds the residual)
    k_gemm_out<<<dim3(HIDDEN / 64, HWN / 64, BB), 256, 0, stream>>>(wo2, fused2, bo, out);
}

// Round 10
// 186.309 us; speedup vs baseline: 2.5929x; 1.0364x over previous
//
#include <hip/hip_runtime.h>
#include <hip/hip_bf16.h>

#define BB 8
#define EMBED 384
#define NH 32
#define HD 12
#define HWN 1024
#define HIDDEN 512
#define KTOT 1536
#define SCALE 0.28867513459481287f

typedef __attribute__((ext_vector_type(8))) unsigned short ushort8;
typedef __attribute__((ext_vector_type(8))) short short8;
typedef __attribute__((ext_vector_type(4))) float f32x4;
typedef __attribute__((ext_vector_type(4))) unsigned short ushort4v;
typedef __attribute__((ext_vector_type(2))) unsigned int uint2v;

static __device__ __forceinline__ float bf2f(unsigned short u) {
    return __uint_as_float(((unsigned int)u) << 16);
}
static __device__ __forceinline__ unsigned short f2bf(float f) {
    unsigned int u = __float_as_uint(f);
    u = u + 0x7FFFu + ((u >> 16) & 1u);   // RNE
    return (unsigned short)(u >> 16);
}
static __device__ __forceinline__ unsigned int cvt_pk_bf16(float lo, float hi) {
    unsigned int r;
    asm("v_cvt_pk_bf16_f32 %0, %1, %2" : "=v"(r) : "v"(lo), "v"(hi));
    return r;
}

// ---------------- f32 -> bf16 weights; Wo duplicated into Wo2[512][1536] ----------------
struct WConv {
    const float* src[7];
    unsigned short* dst[7];
    int start[8];   // prefix over vec4 counts
};

__global__ __launch_bounds__(256) void k_bf16_all(WConv wc) {
    int i = blockIdx.x * 256 + threadIdx.x;
    if (i >= wc.start[7]) return;
    int p = 0;
#pragma unroll
    for (int j = 1; j < 7; ++j) p += (i >= wc.start[j]);
    const int e = i - wc.start[p];
    const f32x4 v = reinterpret_cast<const f32x4*>(wc.src[p])[e];
    ushort4v o;
#pragma unroll
    for (int j = 0; j < 4; ++j) o[j] = f2bf(v[j]);
    if (p == 6) {
        const int row = e / 192, cc = e % 192;
        ushort4v* d = reinterpret_cast<ushort4v*>(wc.dst[6]);
        d[row * 384 + cc] = o;
        d[row * 384 + 192 + cc] = o;
    } else {
        reinterpret_cast<ushort4v*>(wc.dst[p])[e] = o;
    }
}

// ---------------- transpose x (B,C,HW) f32 -> fused2[b][n][768 + s*384 + c] bf16 ----------------
__global__ __launch_bounds__(256) void k_transpose(const float* __restrict__ x0, const float* __restrict__ x1,
                                                   unsigned short* __restrict__ fused2) {
    __shared__ float tile[32][33];
    const int z = blockIdx.z;
    const int s = z >> 3, b = z & 7;
    const float* src = (s ? x1 : x0) + (size_t)b * EMBED * HWN;
    unsigned short* dst = fused2 + (size_t)b * HWN * KTOT + 768 + s * 384;
    const int c0 = blockIdx.x * 32;
    const int n0 = blockIdx.y * 32;
    const int tc = threadIdx.x & 31;
    const int tr = threadIdx.x >> 5;
#pragma unroll
    for (int p = 0; p < 4; ++p) {
        int r = tr + p * 8;
        tile[r][tc] = src[(size_t)(c0 + r) * HWN + n0 + tc];
    }
    __syncthreads();
#pragma unroll
    for (int p = 0; p < 4; ++p) {
        int r = tr + p * 8;
        dst[(size_t)(n0 + r) * KTOT + c0 + tc] = f2bf(tile[tc][r]);
    }
}

// ---------------- bf16 MFMA GEMM: out[o][n] = sum_k A[o][k]*Bt[n][k] + bias[o] ----------------
template <bool F32OUT>
static __device__ __forceinline__ void gemm_core(const unsigned short* __restrict__ A, int lda,
                                                 const unsigned short* __restrict__ Bt, int ldb,
                                                 const float* __restrict__ bias,
                                                 unsigned short* __restrict__ outBf,
                                                 float* __restrict__ outF,
                                                 int K, int bx, int by) {
    __shared__ unsigned short As[64][72];
    __shared__ unsigned short Bs[64][72];
    const int t = threadIdx.x;
    const int lane = t & 63;
    const int wid = t >> 6;
    const int wr = wid >> 1, wc = wid & 1;
    const int o0 = bx * 64, n0 = by * 64;
    const int lrow = t >> 2;
    const int lseg = t & 3;

    f32x4 acc[2][2] = {};

    for (int k0 = 0; k0 < K; k0 += 64) {
        const ushort8* ga = reinterpret_cast<const ushort8*>(A + (size_t)(o0 + lrow) * lda + k0 + lseg * 16);
        const ushort8* gb = reinterpret_cast<const ushort8*>(Bt + (size_t)(n0 + lrow) * ldb + k0 + lseg * 16);
        ushort8 a0 = ga[0], a1 = ga[1];
        ushort8 b0 = gb[0], b1 = gb[1];
        *reinterpret_cast<ushort8*>(&As[lrow][lseg * 16]) = a0;
        *reinterpret_cast<ushort8*>(&As[lrow][lseg * 16 + 8]) = a1;
        *reinterpret_cast<ushort8*>(&Bs[lrow][lseg * 16]) = b0;
        *reinterpret_cast<ushort8*>(&Bs[lrow][lseg * 16 + 8]) = b1;
        __syncthreads();
#pragma unroll
        for (int kk = 0; kk < 2; ++kk) {
            const int ko = kk * 32 + ((lane >> 4) << 3);
            short8 af[2], bfv[2];
            af[0]  = *reinterpret_cast<const short8*>(&As[wr * 32 + (lane & 15)][ko]);
            af[1]  = *reinterpret_cast<const short8*>(&As[wr * 32 + 16 + (lane & 15)][ko]);
            bfv[0] = *reinterpret_cast<const short8*>(&Bs[wc * 32 + (lane & 15)][ko]);
            bfv[1] = *reinterpret_cast<const short8*>(&Bs[wc * 32 + 16 + (lane & 15)][ko]);
#pragma unroll
            for (int i = 0; i < 2; ++i)
#pragma unroll
                for (int j = 0; j < 2; ++j)
                    acc[i][j] = __builtin_amdgcn_mfma_f32_16x16x32_bf16(af[i], bfv[j], acc[i][j], 0, 0, 0);
        }
        __syncthreads();
    }
#pragma unroll
    for (int i = 0; i < 2; ++i) {
#pragma unroll
        for (int j = 0; j < 2; ++j) {
            const int ob = o0 + wr * 32 + i * 16 + ((lane >> 4) << 2);
            const int n  = n0 + wc * 32 + j * 16 + (lane & 15);
#pragma unroll
            for (int r = 0; r < 4; ++r) {
                const int o = ob + r;
                float v = acc[i][j][r] + bias[o];
                if constexpr (F32OUT) outF[(size_t)o * HWN + n] = v;
                else                  outBf[(size_t)o * HWN + n] = f2bf(v);
            }
        }
    }
}

struct QkvTable {
    const unsigned short* W[6];
    const float* bias[6];
    const unsigned short* fused2;
    unsigned short* out[6];
};

__global__ __launch_bounds__(256) void k_gemm_qkv(QkvTable tab) {
    const int z = blockIdx.z;
    const int b = z / 6, p = z % 6;
    const unsigned short* Bt = tab.fused2 + (size_t)b * HWN * KTOT + 768 + (p / 3) * 384;
    gemm_core<false>(tab.W[p], EMBED, Bt, KTOT, tab.bias[p],
                     tab.out[p] + (size_t)b * EMBED * HWN, nullptr,
                     EMBED, blockIdx.x, blockIdx.y);
}

__global__ __launch_bounds__(256) void k_gemm_out(const unsigned short* __restrict__ Wo2,
                                                  const unsigned short* __restrict__ fused2,
                                                  const float* __restrict__ bo,
                                                  float* __restrict__ out) {
    const int b = blockIdx.z;
    gemm_core<true>(Wo2, KTOT, fused2 + (size_t)b * HWN * KTOT, KTOT, bo,
                    nullptr, out + (size_t)b * HIDDEN * HWN,
                    KTOT, blockIdx.x, blockIdx.y);
}

// ---------------- MFMA flash attention v5: round-7-verified 16x16x32 path + 1-deep pipeline ----------------
// Per mc: read P/V frags for PV(mc-1) FIRST (single buffer, reads-before-writes, in-order DS),
// then QK^T(mc)+exp+P-writes, then issue PV(mc-1) MFMAs. The per-mc full lgkm drain between
// QKT and PV is gone; the top-of-loop wait covers only writes issued one MFMA-block earlier.
__global__ __launch_bounds__(256) void k_attn_mfma(const unsigned short* __restrict__ qc,
                                                   const unsigned short* __restrict__ kc,
                                                   const unsigned short* __restrict__ vc,
                                                   const unsigned short* __restrict__ qcb,
                                                   const unsigned short* __restrict__ kcb,
                                                   const unsigned short* __restrict__ vcb,
                                                   unsigned short* __restrict__ fused2) {
    __shared__ unsigned short Ks[512][18];       // [m][d 0..15 + 2 pad], 36B rows (9 dw, coprime 32)
    __shared__ unsigned short Vs[13][520];       // [d][m], row 12 = ones (rowsum trick)
    __shared__ unsigned short Ps[4][4][16][40];  // per-wave P: [i-tile][q][16 m-dw + pad]

    const int bid = blockIdx.x;
    const int inst = bid >> 2, qt = bid & 3;
    const int branch = inst >> 8, b = (inst >> 5) & 7, h = inst & 31;
    const unsigned short* Qg = branch ? qc : qcb;
    const unsigned short* Kg = branch ? kcb : kc;
    const unsigned short* Vg = branch ? vcb : vc;
    const int coff = branch ? 384 : 0;
    const size_t base = ((size_t)b * EMBED + h * HD) * HWN;
    const int t = threadIdx.x;
    const int lane = t & 63, w = t >> 6;
    const int c15 = lane & 15, g = lane >> 4;
    const int n0 = qt * 256;
    const bool ldA = lane < 32;
    const float C2 = SCALE * 1.4426950408889634f;

    // Q B-frags from global, pre-scaled by C2 (16x16x32: k = d = g*8+j, lanes g>=2 are d>=16 zeros)
    short8 qf[4];
#pragma unroll
    for (int i = 0; i < 4; ++i) {
        short8 v = {};
        if (g < 2) {
#pragma unroll
            for (int j = 0; j < 8; ++j) {
                const int d = g * 8 + j;
                if (d < HD)
                    v[j] = (short)f2bf(bf2f(Qg[base + (size_t)d * HWN + n0 + w * 64 + i * 16 + c15]) * C2);
            }
        }
        qf[i] = v;
    }

    f32x4 acc_o[4] = {};
    const f32x4 z4 = {0.f, 0.f, 0.f, 0.f};
    const int vrow = (c15 < 12) ? c15 : 12;   // 12 = ones row -> col 12 = row-sum

    for (int phase = 0; phase < 2; ++phase) {
        const int m0 = phase << 9;
        __syncthreads();   // prior-phase reads (incl. drained PV) done
        // --- stage K: wave w owns d-rows 4w..4w+3 (w=3 -> zeros). 128B-coalesced gathers.
        {
            const size_t kb = base + (size_t)(4 * w) * HWN + m0;
#pragma unroll
            for (int it = 0; it < 8; ++it) {
                const int m = it * 64 + lane;
                unsigned int da = 0, db = 0;
                if (w < 3) {
                    da = (unsigned int)Kg[kb + m] | ((unsigned int)Kg[kb + HWN + m] << 16);
                    db = (unsigned int)Kg[kb + 2 * HWN + m] | ((unsigned int)Kg[kb + 3 * HWN + m] << 16);
                }
                unsigned int* p = reinterpret_cast<unsigned int*>(&Ks[m][w * 4]);
                p[0] = da;
                p[1] = db;
            }
        }
        // --- stage V [d][512] vectorized + ones row (d = 12)
#pragma unroll
        for (int i = 0; i < 4; ++i) {
            const int idx = i * 256 + t;
            if (idx < 832) {
                const int d = idx >> 6, m8 = (idx & 63) << 3;
                ushort8 v;
                if (d < HD) {
                    v = *reinterpret_cast<const ushort8*>(&Vg[base + (size_t)d * HWN + m0 + m8]);
                } else {
#pragma unroll
                    for (int j = 0; j < 8; ++j) v[j] = 0x3F80;   // 1.0 bf16
                }
                *reinterpret_cast<ushort8*>(&Vs[d][m8]) = v;
            }
        }
        __syncthreads();

        for (int mc = 0; mc < 16; ++mc) {
            const int mb = mc << 5;
            // --- PV(mc-1) operand loads FIRST (reads-before-writes; in-order DS makes this safe)
            short8 paf[4];
            short8 bvp = {};
            if (mc > 0) {
                asm volatile("s_waitcnt lgkmcnt(0)" ::: "memory");   // P writes of mc-1 committed
                __builtin_amdgcn_sched_barrier(0);
#pragma unroll
                for (int i = 0; i < 4; ++i)
                    paf[i] = *reinterpret_cast<const short8*>(&Ps[w][i][c15][g * 8]);
                bvp = *reinterpret_cast<const short8*>(&Vs[vrow][(mb - 32) + g * 8]);
            }
            // --- QK^T(mc) + exp + P writes
            short8 kf0 = {}, kf1 = {};
            if (ldA) {
                union { short8 v; unsigned int u[4]; } a, bb;
                const unsigned int* p0 = reinterpret_cast<const unsigned int*>(&Ks[mb + c15][g * 8]);
                a.u[0] = p0[0]; a.u[1] = p0[1]; a.u[2] = p0[2]; a.u[3] = p0[3];
                const unsigned int* p1 = reinterpret_cast<const unsigned int*>(&Ks[mb + 16 + c15][g * 8]);
                bb.u[0] = p1[0]; bb.u[1] = p1[1]; bb.u[2] = p1[2]; bb.u[3] = p1[3];
                kf0 = a.v; kf1 = bb.v;
            }
#pragma unroll
            for (int i = 0; i < 4; ++i) {
                // swapped QK^T: D[m-row][q-col]; lane: q = c15, m = g*4+r (+16 for s1)
                f32x4 s0 = __builtin_amdgcn_mfma_f32_16x16x32_bf16(kf0, qf[i], z4, 0, 0, 0);
                f32x4 s1 = __builtin_amdgcn_mfma_f32_16x16x32_bf16(kf1, qf[i], z4, 0, 0, 0);
                float p0[4], p1[4];
#pragma unroll
                for (int r = 0; r < 4; ++r) {
                    p0[r] = __builtin_amdgcn_exp2f(s0[r]);
                    p1[r] = __builtin_amdgcn_exp2f(s1[r]);
                }
                uint2v u0, u1;
                u0[0] = cvt_pk_bf16(p0[0], p0[1]);
                u0[1] = cvt_pk_bf16(p0[2], p0[3]);
                u1[0] = cvt_pk_bf16(p1[0], p1[1]);
                u1[1] = cvt_pk_bf16(p1[2], p1[3]);
                *reinterpret_cast<uint2v*>(&Ps[w][i][c15][g * 4]) = u0;
                *reinterpret_cast<uint2v*>(&Ps[w][i][c15][16 + g * 4]) = u1;
            }
            // --- PV(mc-1) MFMAs from registers (independent of QKT(mc) above)
            if (mc > 0) {
#pragma unroll
                for (int i = 0; i < 4; ++i)
                    acc_o[i] = __builtin_amdgcn_mfma_f32_16x16x32_bf16(paf[i], bvp, acc_o[i], 0, 0, 0);
            }
        }
        // --- drain: PV(15) of this phase (before next phase's staging overwrites Vs)
        {
            asm volatile("s_waitcnt lgkmcnt(0)" ::: "memory");
            __builtin_amdgcn_sched_barrier(0);
            const short8 bvp = *reinterpret_cast<const short8*>(&Vs[vrow][480 + g * 8]);
#pragma unroll
            for (int i = 0; i < 4; ++i) {
                const short8 paf = *reinterpret_cast<const short8*>(&Ps[w][i][c15][g * 8]);
                acc_o[i] = __builtin_amdgcn_mfma_f32_16x16x32_bf16(paf, bvp, acc_o[i], 0, 0, 0);
            }
        }
    }

    // inverse row-sums from the ones-column (lane c15 = 12 of each g-group)
    float invq[4][4];
#pragma unroll
    for (int i = 0; i < 4; ++i)
#pragma unroll
        for (int r = 0; r < 4; ++r)
            invq[i][r] = 1.0f / __shfl(acc_o[i][r], (lane & 48) | 12);

    __syncthreads();   // all PV reads of Ps done before Ot overwrite
    unsigned short* Ot = &Ps[w][0][0][0];   // [12 d][68] per wave
    if (c15 < HD) {
#pragma unroll
        for (int i = 0; i < 4; ++i) {
            const unsigned int w0 = (unsigned int)f2bf(acc_o[i][0] * invq[i][0]) |
                                    ((unsigned int)f2bf(acc_o[i][1] * invq[i][1]) << 16);
            const unsigned int w1 = (unsigned int)f2bf(acc_o[i][2] * invq[i][2]) |
                                    ((unsigned int)f2bf(acc_o[i][3] * invq[i][3]) << 16);
            uint2v u; u[0] = w0; u[1] = w1;
            *reinterpret_cast<uint2v*>(&Ot[c15 * 68 + i * 16 + g * 4]) = u;
        }
    }
    __syncthreads();
    unsigned int rr[6];
#pragma unroll
    for (int dp = 0; dp < 6; ++dp)
        rr[dp] = (unsigned int)Ot[(2 * dp) * 68 + lane] | ((unsigned int)Ot[(2 * dp + 1) * 68 + lane] << 16);
    unsigned short* dst = fused2 + ((size_t)b * HWN + n0 + t) * KTOT + coff + h * HD;
#pragma unroll
    for (int q = 0; q < 3; ++q) {
        uint2v u; u[0] = rr[2 * q]; u[1] = rr[2 * q + 1];
        *reinterpret_cast<uint2v*>(&dst[q * 4]) = u;
    }
}

extern "C" void kernel_launch(void* const* d_in, const int* in_sizes, int n_in,
                              void* d_out, int out_size, void* d_ws, size_t ws_size,
                              hipStream_t stream) {
    (void)in_sizes; (void)n_in; (void)out_size; (void)ws_size;
    const float* x   = (const float*)d_in[0];
    const float* xbp = (const float*)d_in[1];
    const float* Wq  = (const float*)d_in[2];  const float* bq  = (const float*)d_in[3];
    const float* Wk  = (const float*)d_in[4];  const float* bk  = (const float*)d_in[5];
    const float* Wv  = (const float*)d_in[6];  const float* bv  = (const float*)d_in[7];
    const float* Wqb = (const float*)d_in[8];  const float* bqb = (const float*)d_in[9];
    const float* Wkb = (const float*)d_in[10]; const float* bkb = (const float*)d_in[11];
    const float* Wvb = (const float*)d_in[12]; const float* bvb = (const float*)d_in[13];
    const float* Wo  = (const float*)d_in[14]; const float* bo  = (const float*)d_in[15];
    float* out = (float*)d_out;

    char* ws = (char*)d_ws;
    size_t off = 0;
    auto alloc = [&](size_t bytes) -> void* {
        void* p = ws + off;
        off = (off + bytes + 255) & ~(size_t)255;
        return p;
    };
    unsigned short* wbf[6];
    for (int i = 0; i < 6; ++i) wbf[i] = (unsigned short*)alloc((size_t)EMBED * EMBED * 2);
    unsigned short* wo2 = (unsigned short*)alloc((size_t)HIDDEN * KTOT * 2);
    unsigned short* qkv[6];
    for (int i = 0; i < 6; ++i) qkv[i] = (unsigned short*)alloc((size_t)BB * EMBED * HWN * 2);
    unsigned short* fused2 = (unsigned short*)alloc((size_t)BB * HWN * KTOT * 2);

    // 1) weights -> bf16 (Wo duplicated into Wo2)
    WConv wc;
    const float* wsrc[7] = {Wq, Wk, Wv, Wqb, Wkb, Wvb, Wo};
    unsigned short* wdst[7] = {wbf[0], wbf[1], wbf[2], wbf[3], wbf[4], wbf[5], wo2};
    int acc4 = 0;
    for (int i = 0; i < 7; ++i) {
        const int n = (i < 6) ? EMBED * EMBED : HIDDEN * 768;
        wc.src[i] = wsrc[i];
        wc.dst[i] = wdst[i];
        wc.start[i] = acc4;
        acc4 += n / 4;
    }
    wc.start[7] = acc4;
    k_bf16_all<<<(acc4 + 255) / 256, 256, 0, stream>>>(wc);

    // 2) x, x_bpf -> token-major bf16 into fused2 cols 768..1535
    k_transpose<<<dim3(EMBED / 32, HWN / 32, 16), 256, 0, stream>>>(x, xbp, fused2);

    // 3) six QKV projections
    QkvTable tab;
    tab.W[0] = wbf[0]; tab.W[1] = wbf[1]; tab.W[2] = wbf[2];
    tab.W[3] = wbf[3]; tab.W[4] = wbf[4]; tab.W[5] = wbf[5];
    tab.bias[0] = bq; tab.bias[1] = bk; tab.bias[2] = bv;
    tab.bias[3] = bqb; tab.bias[4] = bkb; tab.bias[5] = bvb;
    tab.fused2 = fused2;
    for (int i = 0; i < 6; ++i) tab.out[i] = qkv[i];
    k_gemm_qkv<<<dim3(EMBED / 64, HWN / 64, BB * 6), 256, 0, stream>>>(tab);

    // 4) MFMA attention -> fused2 cols 0..767
    k_attn_mfma<<<dim3(2048), 256, 0, stream>>>(qkv[0], qkv[1], qkv[2], qkv[3], qkv[4], qkv[5],
                                                fused2);

    // 5) out = Wo2 . fused2 + bo   (K=1536 folds the residual)
    k_gemm_out<<<dim3(HIDDEN / 64, HWN / 64, BB), 256, 0, stream>>>(wo2, fused2, bo, out);
}

// Round 11
// 166.357 us; speedup vs baseline: 2.9038x; 1.1199x over previous
//
#include <hip/hip_runtime.h>
#include <hip/hip_bf16.h>

#define BB 8
#define EMBED 384
#define NH 32
#define HD 12
#define HWN 1024
#define HIDDEN 512
#define KTOT 1536
#define SCALE 0.28867513459481287f

typedef __attribute__((ext_vector_type(8))) unsigned short ushort8;
typedef __attribute__((ext_vector_type(8))) short short8;
typedef __attribute__((ext_vector_type(4))) float f32x4;
typedef __attribute__((ext_vector_type(16))) float f32x16;
typedef __attribute__((ext_vector_type(4))) unsigned short ushort4v;
typedef __attribute__((ext_vector_type(2))) unsigned int uint2v;

static __device__ __forceinline__ float bf2f(unsigned short u) {
    return __uint_as_float(((unsigned int)u) << 16);
}
static __device__ __forceinline__ unsigned short f2bf(float f) {
    unsigned int u = __float_as_uint(f);
    u = u + 0x7FFFu + ((u >> 16) & 1u);   // RNE
    return (unsigned short)(u >> 16);
}
static __device__ __forceinline__ unsigned int cvt_pk_bf16(float lo, float hi) {
    unsigned int r;
    asm("v_cvt_pk_bf16_f32 %0, %1, %2" : "=v"(r) : "v"(lo), "v"(hi));
    return r;
}

// ---------------- f32 -> bf16 weights; Wo duplicated into Wo2[512][1536] ----------------
struct WConv {
    const float* src[7];
    unsigned short* dst[7];
    int start[8];   // prefix over vec4 counts
};

__global__ __launch_bounds__(256) void k_bf16_all(WConv wc) {
    int i = blockIdx.x * 256 + threadIdx.x;
    if (i >= wc.start[7]) return;
    int p = 0;
#pragma unroll
    for (int j = 1; j < 7; ++j) p += (i >= wc.start[j]);
    const int e = i - wc.start[p];
    const f32x4 v = reinterpret_cast<const f32x4*>(wc.src[p])[e];
    ushort4v o;
#pragma unroll
    for (int j = 0; j < 4; ++j) o[j] = f2bf(v[j]);
    if (p == 6) {
        const int row = e / 192, cc = e % 192;
        ushort4v* d = reinterpret_cast<ushort4v*>(wc.dst[6]);
        d[row * 384 + cc] = o;
        d[row * 384 + 192 + cc] = o;
    } else {
        reinterpret_cast<ushort4v*>(wc.dst[p])[e] = o;
    }
}

// ---------------- transpose x (B,C,HW) f32 -> fused2[b][n][768 + s*384 + c] bf16 ----------------
__global__ __launch_bounds__(256) void k_transpose(const float* __restrict__ x0, const float* __restrict__ x1,
                                                   unsigned short* __restrict__ fused2) {
    __shared__ float tile[32][33];
    const int z = blockIdx.z;
    const int s = z >> 3, b = z & 7;
    const float* src = (s ? x1 : x0) + (size_t)b * EMBED * HWN;
    unsigned short* dst = fused2 + (size_t)b * HWN * KTOT + 768 + s * 384;
    const int c0 = blockIdx.x * 32;
    const int n0 = blockIdx.y * 32;
    const int tc = threadIdx.x & 31;
    const int tr = threadIdx.x >> 5;
#pragma unroll
    for (int p = 0; p < 4; ++p) {
        int r = tr + p * 8;
        tile[r][tc] = src[(size_t)(c0 + r) * HWN + n0 + tc];
    }
    __syncthreads();
#pragma unroll
    for (int p = 0; p < 4; ++p) {
        int r = tr + p * 8;
        dst[(size_t)(n0 + r) * KTOT + c0 + tc] = f2bf(tile[tc][r]);
    }
}

// ---------------- bf16 MFMA GEMM: out[o][n] = sum_k A[o][k]*Bt[n][k] + bias[o] ----------------
template <bool F32OUT>
static __device__ __forceinline__ void gemm_core(const unsigned short* __restrict__ A, int lda,
                                                 const unsigned short* __restrict__ Bt, int ldb,
                                                 const float* __restrict__ bias,
                                                 unsigned short* __restrict__ outBf,
                                                 float* __restrict__ outF,
                                                 int K, int bx, int by) {
    __shared__ unsigned short As[64][72];
    __shared__ unsigned short Bs[64][72];
    const int t = threadIdx.x;
    const int lane = t & 63;
    const int wid = t >> 6;
    const int wr = wid >> 1, wc = wid & 1;
    const int o0 = bx * 64, n0 = by * 64;
    const int lrow = t >> 2;
    const int lseg = t & 3;

    f32x4 acc[2][2] = {};

    for (int k0 = 0; k0 < K; k0 += 64) {
        const ushort8* ga = reinterpret_cast<const ushort8*>(A + (size_t)(o0 + lrow) * lda + k0 + lseg * 16);
        const ushort8* gb = reinterpret_cast<const ushort8*>(Bt + (size_t)(n0 + lrow) * ldb + k0 + lseg * 16);
        ushort8 a0 = ga[0], a1 = ga[1];
        ushort8 b0 = gb[0], b1 = gb[1];
        *reinterpret_cast<ushort8*>(&As[lrow][lseg * 16]) = a0;
        *reinterpret_cast<ushort8*>(&As[lrow][lseg * 16 + 8]) = a1;
        *reinterpret_cast<ushort8*>(&Bs[lrow][lseg * 16]) = b0;
        *reinterpret_cast<ushort8*>(&Bs[lrow][lseg * 16 + 8]) = b1;
        __syncthreads();
#pragma unroll
        for (int kk = 0; kk < 2; ++kk) {
            const int ko = kk * 32 + ((lane >> 4) << 3);
            short8 af[2], bfv[2];
            af[0]  = *reinterpret_cast<const short8*>(&As[wr * 32 + (lane & 15)][ko]);
            af[1]  = *reinterpret_cast<const short8*>(&As[wr * 32 + 16 + (lane & 15)][ko]);
            bfv[0] = *reinterpret_cast<const short8*>(&Bs[wc * 32 + (lane & 15)][ko]);
            bfv[1] = *reinterpret_cast<const short8*>(&Bs[wc * 32 + 16 + (lane & 15)][ko]);
#pragma unroll
            for (int i = 0; i < 2; ++i)
#pragma unroll
                for (int j = 0; j < 2; ++j)
                    acc[i][j] = __builtin_amdgcn_mfma_f32_16x16x32_bf16(af[i], bfv[j], acc[i][j], 0, 0, 0);
        }
        __syncthreads();
    }
#pragma unroll
    for (int i = 0; i < 2; ++i) {
#pragma unroll
        for (int j = 0; j < 2; ++j) {
            const int ob = o0 + wr * 32 + i * 16 + ((lane >> 4) << 2);
            const int n  = n0 + wc * 32 + j * 16 + (lane & 15);
#pragma unroll
            for (int r = 0; r < 4; ++r) {
                const int o = ob + r;
                float v = acc[i][j][r] + bias[o];
                if constexpr (F32OUT) outF[(size_t)o * HWN + n] = v;
                else                  outBf[(size_t)o * HWN + n] = f2bf(v);
            }
        }
    }
}

struct QkvTable {
    const unsigned short* W[6];
    const float* bias[6];
    const unsigned short* fused2;
    unsigned short* out[6];
};

__global__ __launch_bounds__(256) void k_gemm_qkv(QkvTable tab) {
    const int z = blockIdx.z;
    const int b = z / 6, p = z % 6;
    const unsigned short* Bt = tab.fused2 + (size_t)b * HWN * KTOT + 768 + (p / 3) * 384;
    gemm_core<false>(tab.W[p], EMBED, Bt, KTOT, tab.bias[p],
                     tab.out[p] + (size_t)b * EMBED * HWN, nullptr,
                     EMBED, blockIdx.x, blockIdx.y);
}

__global__ __launch_bounds__(256) void k_gemm_out(const unsigned short* __restrict__ Wo2,
                                                  const unsigned short* __restrict__ fused2,
                                                  const float* __restrict__ bo,
                                                  float* __restrict__ out) {
    const int b = blockIdx.z;
    gemm_core<true>(Wo2, KTOT, fused2 + (size_t)b * HWN * KTOT, KTOT, bo,
                    nullptr, out + (size_t)b * HIDDEN * HWN,
                    KTOT, blockIdx.x, blockIdx.y);
}

// ---------------- MFMA flash attention v6: 32x32x16, all-register P via sigma-permuted V ----------------
// QKT swapped (A=K,B=Q): C[q=lane&31] holds P[m(reg)][q], m(reg)=(reg&3)+8*(reg>>2)+4*hi.
// Packed in register order this IS a PV A-fragment if V's k-rows are permuted by
// sigma = {0,1,2,3,8,9,10,11 | 4,5,6,7,12,13,14,15}: realized by reading V at mb+hi*4 / mb+8+hi*4.
// No LDS P, no waits in the hot loop. Ones V-row 12 gives rowsums in output col 12.
__global__ __launch_bounds__(256) void k_attn_mfma(const unsigned short* __restrict__ qc,
                                                   const unsigned short* __restrict__ kc,
                                                   const unsigned short* __restrict__ vc,
                                                   const unsigned short* __restrict__ qcb,
                                                   const unsigned short* __restrict__ kcb,
                                                   const unsigned short* __restrict__ vcb,
                                                   unsigned short* __restrict__ fused2) {
    __shared__ unsigned short Ks[512][18];   // [m][d 0..15 + 2 pad], 36B rows (9 dw, coprime 32)
    __shared__ unsigned short Vs[13][520];   // [d][m], row 12 = ones

    const int bid = blockIdx.x;
    const int inst = bid >> 3, qt = bid & 7;
    const int branch = inst >> 8, b = (inst >> 5) & 7, h = inst & 31;
    const unsigned short* Qg = branch ? qc : qcb;
    const unsigned short* Kg = branch ? kcb : kc;
    const unsigned short* Vg = branch ? vcb : vc;
    const int coff = branch ? 384 : 0;
    const size_t base = ((size_t)b * EMBED + h * HD) * HWN;
    const int t = threadIdx.x;
    const int lane = t & 63, w = t >> 6;
    const int q31 = lane & 31, hi = lane >> 5;
    const int n0 = qt * 128;
    const float C2 = SCALE * 1.4426950408889634f;

    // Q B-frag (32x32x16): lane (q31, hi) holds Q[d=hi*8+j][q = n0 + w*32 + q31], pre-scaled by C2
    short8 qf = {};
    {
        const int qg = n0 + w * 32 + q31;
#pragma unroll
        for (int j = 0; j < 8; ++j) {
            const int d = hi * 8 + j;
            if (d < HD)
                qf[j] = (short)f2bf(bf2f(Qg[base + (size_t)d * HWN + qg]) * C2);
        }
    }

    f32x16 acc, z16;
#pragma unroll
    for (int r = 0; r < 16; ++r) { acc[r] = 0.f; z16[r] = 0.f; }
    const int vrow = (q31 < HD) ? q31 : 12;   // lanes d>=12 read ones row (outputs discarded)

    for (int phase = 0; phase < 2; ++phase) {
        const int m0 = phase << 9;
        __syncthreads();   // prior-phase reads done
        // --- stage K: wave w owns d-rows 4w..4w+3 (w=3 -> zeros). 128B-coalesced gathers.
        {
            const size_t kb = base + (size_t)(4 * w) * HWN + m0;
#pragma unroll
            for (int it = 0; it < 8; ++it) {
                const int m = it * 64 + lane;
                unsigned int da = 0, db = 0;
                if (w < 3) {
                    da = (unsigned int)Kg[kb + m] | ((unsigned int)Kg[kb + HWN + m] << 16);
                    db = (unsigned int)Kg[kb + 2 * HWN + m] | ((unsigned int)Kg[kb + 3 * HWN + m] << 16);
                }
                unsigned int* p = reinterpret_cast<unsigned int*>(&Ks[m][w * 4]);
                p[0] = da;
                p[1] = db;
            }
        }
        // --- stage V: wave w<3 owns d-rows 4w..4w+3; w==3 writes the ones row (d=12)
        if (w < 3) {
#pragma unroll
            for (int r = 0; r < 4; ++r) {
                const int d = 4 * w + r;
                *reinterpret_cast<ushort8*>(&Vs[d][lane * 8]) =
                    *reinterpret_cast<const ushort8*>(&Vg[base + (size_t)d * HWN + m0 + lane * 8]);
            }
        } else {
            ushort8 ones;
#pragma unroll
            for (int j = 0; j < 8; ++j) ones[j] = 0x3F80;
            *reinterpret_cast<ushort8*>(&Vs[12][lane * 8]) = ones;
        }
        __syncthreads();

        for (int mc = 0; mc < 16; ++mc) {
            const int mb = mc << 5;
            // K A-frag: lane (m-local = q31, hi) = K[mb+q31][d = hi*8+j]; dword loads (36B rows)
            union { short8 v; unsigned int u[4]; } kf;
            {
                const unsigned int* kp = reinterpret_cast<const unsigned int*>(&Ks[mb + q31][hi * 8]);
                kf.u[0] = kp[0]; kf.u[1] = kp[1]; kf.u[2] = kp[2]; kf.u[3] = kp[3];
            }
            // V B-frags, sigma-permuted k-rows: PV1 m {0..3,8..11}+4hi, PV2 +16
            union { short8 v; uint2v u2[2]; } vf1, vf2;
            vf1.u2[0] = *reinterpret_cast<const uint2v*>(&Vs[vrow][mb + hi * 4]);
            vf1.u2[1] = *reinterpret_cast<const uint2v*>(&Vs[vrow][mb + 8 + hi * 4]);
            vf2.u2[0] = *reinterpret_cast<const uint2v*>(&Vs[vrow][mb + 16 + hi * 4]);
            vf2.u2[1] = *reinterpret_cast<const uint2v*>(&Vs[vrow][mb + 24 + hi * 4]);
            // QKT: C reg r = P[m=(r&3)+8*(r>>2)+4hi][q=q31]
            const f32x16 s = __builtin_amdgcn_mfma_f32_32x32x16_bf16(kf.v, qf, z16, 0, 0, 0);
            union { short8 v; unsigned int u[4]; } p1, p2;
#pragma unroll
            for (int r = 0; r < 4; ++r) {
                p1.u[r] = cvt_pk_bf16(__builtin_amdgcn_exp2f(s[2 * r]),
                                      __builtin_amdgcn_exp2f(s[2 * r + 1]));
                p2.u[r] = cvt_pk_bf16(__builtin_amdgcn_exp2f(s[8 + 2 * r]),
                                      __builtin_amdgcn_exp2f(s[8 + 2 * r + 1]));
            }
            acc = __builtin_amdgcn_mfma_f32_32x32x16_bf16(p1.v, vf1.v, acc, 0, 0, 0);
            acc = __builtin_amdgcn_mfma_f32_32x32x16_bf16(p2.v, vf2.v, acc, 0, 0, 0);
        }
    }

    // inverse row-sums: output col 12 (ones row) at lane (lane&32)|12, same reg
    float invq[16];
#pragma unroll
    for (int r = 0; r < 16; ++r)
        invq[r] = 1.0f / __shfl(acc[r], (lane & 32) | 12);

    __syncthreads();   // all Ks/Vs reads done before Ot overwrites Ks
    // Ot per wave: [12 d][32 q] shorts, reusing Ks storage
    unsigned short* OtW = &Ks[0][0] + w * 384;
    if (q31 < HD) {
#pragma unroll
        for (int r2 = 0; r2 < 8; ++r2) {
            const int r = 2 * r2;
            const int q = (r & 3) + 8 * (r >> 2) + 4 * hi;
            const unsigned int dw = (unsigned int)f2bf(acc[r] * invq[r]) |
                                    ((unsigned int)f2bf(acc[r + 1] * invq[r + 1]) << 16);
            *reinterpret_cast<unsigned int*>(&OtW[q31 * 32 + q]) = dw;
        }
    }
    __syncthreads();
    // store: thread t -> q = t>>1 (128 q/block), half = t&1 covers d 0..5 / 6..11
    {
        const int q = t >> 1, half = t & 1;
        const unsigned short* Osrc = &Ks[0][0] + (q >> 5) * 384 + (half * 6) * 32 + (q & 31);
        const unsigned int w0 = (unsigned int)Osrc[0]   | ((unsigned int)Osrc[32]  << 16);
        const unsigned int w1 = (unsigned int)Osrc[64]  | ((unsigned int)Osrc[96]  << 16);
        const unsigned int w2 = (unsigned int)Osrc[128] | ((unsigned int)Osrc[160] << 16);
        unsigned int* dst = reinterpret_cast<unsigned int*>(
            fused2 + ((size_t)b * HWN + n0 + q) * KTOT + coff + h * HD + half * 6);
        dst[0] = w0; dst[1] = w1; dst[2] = w2;
    }
}

extern "C" void kernel_launch(void* const* d_in, const int* in_sizes, int n_in,
                              void* d_out, int out_size, void* d_ws, size_t ws_size,
                              hipStream_t stream) {
    (void)in_sizes; (void)n_in; (void)out_size; (void)ws_size;
    const float* x   = (const float*)d_in[0];
    const float* xbp = (const float*)d_in[1];
    const float* Wq  = (const float*)d_in[2];  const float* bq  = (const float*)d_in[3];
    const float* Wk  = (const float*)d_in[4];  const float* bk  = (const float*)d_in[5];
    const float* Wv  = (const float*)d_in[6];  const float* bv  = (const float*)d_in[7];
    const float* Wqb = (const float*)d_in[8];  const float* bqb = (const float*)d_in[9];
    const float* Wkb = (const float*)d_in[10]; const float* bkb = (const float*)d_in[11];
    const float* Wvb = (const float*)d_in[12]; const float* bvb = (const float*)d_in[13];
    const float* Wo  = (const float*)d_in[14]; const float* bo  = (const float*)d_in[15];
    float* out = (float*)d_out;

    char* ws = (char*)d_ws;
    size_t off = 0;
    auto alloc = [&](size_t bytes) -> void* {
        void* p = ws + off;
        off = (off + bytes + 255) & ~(size_t)255;
        return p;
    };
    unsigned short* wbf[6];
    for (int i = 0; i < 6; ++i) wbf[i] = (unsigned short*)alloc((size_t)EMBED * EMBED * 2);
    unsigned short* wo2 = (unsigned short*)alloc((size_t)HIDDEN * KTOT * 2);
    unsigned short* qkv[6];
    for (int i = 0; i < 6; ++i) qkv[i] = (unsigned short*)alloc((size_t)BB * EMBED * HWN * 2);
    unsigned short* fused2 = (unsigned short*)alloc((size_t)BB * HWN * KTOT * 2);

    // 1) weights -> bf16 (Wo duplicated into Wo2)
    WConv wc;
    const float* wsrc[7] = {Wq, Wk, Wv, Wqb, Wkb, Wvb, Wo};
    unsigned short* wdst[7] = {wbf[0], wbf[1], wbf[2], wbf[3], wbf[4], wbf[5], wo2};
    int acc4 = 0;
    for (int i = 0; i < 7; ++i) {
        const int n = (i < 6) ? EMBED * EMBED : HIDDEN * 768;
        wc.src[i] = wsrc[i];
        wc.dst[i] = wdst[i];
        wc.start[i] = acc4;
        acc4 += n / 4;
    }
    wc.start[7] = acc4;
    k_bf16_all<<<(acc4 + 255) / 256, 256, 0, stream>>>(wc);

    // 2) x, x_bpf -> token-major bf16 into fused2 cols 768..1535
    k_transpose<<<dim3(EMBED / 32, HWN / 32, 16), 256, 0, stream>>>(x, xbp, fused2);

    // 3) six QKV projections
    QkvTable tab;
    tab.W[0] = wbf[0]; tab.W[1] = wbf[1]; tab.W[2] = wbf[2];
    tab.W[3] = wbf[3]; tab.W[4] = wbf[4]; tab.W[5] = wbf[5];
    tab.bias[0] = bq; tab.bias[1] = bk; tab.bias[2] = bv;
    tab.bias[3] = bqb; tab.bias[4] = bkb; tab.bias[5] = bvb;
    tab.fused2 = fused2;
    for (int i = 0; i < 6; ++i) tab.out[i] = qkv[i];
    k_gemm_qkv<<<dim3(EMBED / 64, HWN / 64, BB * 6), 256, 0, stream>>>(tab);

    // 4) MFMA attention -> fused2 cols 0..767 (grid = 512 instances x 8 q-tiles of 128)
    k_attn_mfma<<<dim3(4096), 256, 0, stream>>>(qkv[0], qkv[1], qkv[2], qkv[3], qkv[4], qkv[5],
                                                fused2);

    // 5) out = Wo2 . fused2 + bo   (K=1536 folds the residual)
    k_gemm_out<<<dim3(HIDDEN / 64, HWN / 64, BB), 256, 0, stream>>>(wo2, fused2, bo, out);
}